// Round 10
// baseline (299.039 us; speedup 1.0000x reference)
//
#include <hip/hip_runtime.h>
#include <hip/hip_bf16.h>
#include <stdint.h>

typedef __bf16 bf16;
typedef __bf16 bf16x4 __attribute__((ext_vector_type(4)));
typedef __bf16 bf16x8 __attribute__((ext_vector_type(8)));
typedef float floatx4 __attribute__((ext_vector_type(4)));
typedef float floatx8 __attribute__((ext_vector_type(8)));

#define MFMA16(A, B, C) __builtin_amdgcn_mfma_f32_16x16x32_bf16(A, B, C, 0, 0, 0)

constexpr int Sc = 2048, HIDc = 2048, NHc = 32, NKVc = 8, HDc = 64;
constexpr float kScale = 0.125f;   // HD^-0.5
constexpr float kMax = 9.0f;       // static softmax max: |s*scale| <= 8 (|q|=|k|=8)

// async 16B global -> LDS (wave-uniform base + lane*16 on the LDS side)
__device__ __forceinline__ void async16(const bf16* g, bf16* l) {
  __builtin_amdgcn_global_load_lds(
      (const __attribute__((address_space(1))) void*)g,
      (__attribute__((address_space(3))) void*)l, 16, 0, 0);
}

// ---------------------------------------------------------------------------
// f32 -> bf16 conversion for hs + 4 weight matrices (blockIdx.y selects).
// ---------------------------------------------------------------------------
__global__ __launch_bounds__(256)
void cvt5(const float* __restrict__ s0, bf16* __restrict__ d0, int n0,
          const float* __restrict__ s1, bf16* __restrict__ d1, int n1,
          const float* __restrict__ s2, bf16* __restrict__ d2, int n2,
          const float* __restrict__ s3, bf16* __restrict__ d3, int n3,
          const float* __restrict__ s4, bf16* __restrict__ d4, int n4)
{
  const float* s; bf16* d; int n;
  switch (blockIdx.y) {
    case 0: s = s0; d = d0; n = n0; break;
    case 1: s = s1; d = d1; n = n1; break;
    case 2: s = s2; d = d2; n = n2; break;
    case 3: s = s3; d = d3; n = n3; break;
    default: s = s4; d = d4; n = n4; break;
  }
  const size_t stride = (size_t)gridDim.x * blockDim.x * 8;
  for (size_t i = ((size_t)blockIdx.x * blockDim.x + threadIdx.x) * 8;
       i < (size_t)n; i += stride) {
    floatx8 f = *(const floatx8*)(s + i);
    bf16x8 o;
#pragma unroll
    for (int j = 0; j < 8; ++j) o[j] = (bf16)f[j];
    *(bf16x8*)(d + i) = o;
  }
}

// ---------------------------------------------------------------------------
// 128x128 pipelined GEMM core, 256 threads / 4 waves (2x2, 64x64 per wave).
// C(128x128) = A(128xK) @ Bw(128xK)^T, bf16 in, fp32 accum. BK=64 as two
// K-half images of 8 KB each; LDS = 2buf x 2half x (A,B) = 64 KiB
// -> 2 blocks/CU resident (cross-block TLP covers the ds_read drains).
// Packed LDS rows: 128B row = M-halves (lrow, lrow+64) as 16B slots 0-3/4-7,
// slot XOR (lrow&7), involution pre-applied to the GLOBAL source address
// (linear LDS dest for global_load_lds). Conflicts measured 0 (round 6).
// Schedule per K-tile: {phA: read kk0 frags, stage t+1 kk1; BAR; 16 MFMA;
// BAR; phB: read kk1, stage t+2 kk0; BAR; 16 MFMA; gate; BAR}.
// TAIL-RACE FIX (r9 post-mortem): when phase B skips its stage (t+2 >= NT),
// the last-4 outstanding loads at the gate are S_A(t) = tile t+1's kk1, so
// vmcnt(4) would leave them UNCERTIFIED and the final tile's phase B could
// read in-flight LDS (rounds 6-8 carried this latent race; r9's timing
// exposed it -> absmax 0.438 nondeterministic). Gate is vmcnt(4) only while
// a phase-B stage was issued this iteration, else vmcnt(0) (full drain on
// the final two gates only; ~2/32 iterations).
// ---------------------------------------------------------------------------
__device__ __forceinline__
void gemm128_core(const bf16* __restrict__ A, const bf16* __restrict__ Bw,
                  int K, int m0, int n0, bf16* __restrict__ lds,
                  floatx4 (&acc)[4][4])
{
  constexpr int IH = 128 * 32;      // elements per K-half image (8 KB)

  const int tid  = threadIdx.x;     // 0..255
  const int lane = tid & 63;
  const int w    = tid >> 6;        // 0..3
  const int r    = lane & 15;
  const int quad = lane >> 4;
  const int wm   = w >> 1;          // 2 wave rows
  const int wn   = w & 1;           // 2 wave cols
  const int NT   = K >> 6;

  // staging sources, pre-swizzled: chunk ch=(i*256+tid) -> lrow=ch>>3 (0..63),
  // global slot sl=(ch&7)^(lrow&7); sl>>2 = M-half, sl&3 = 16B K-granule.
  const bf16* gA[2]; const bf16* gB[2];
#pragma unroll
  for (int i = 0; i < 2; ++i) {
    const int ch = i * 256 + tid;
    const int lrow = ch >> 3, sl = (ch & 7) ^ (lrow & 7);
    gA[i] = A  + (size_t)(m0 + (sl >> 2) * 64 + lrow) * K + (sl & 3) * 8;
    gB[i] = Bw + (size_t)(n0 + (sl >> 2) * 64 + lrow) * K + (sl & 3) * 8;
  }

  auto stA = [&](int kt, int s, int kk) {
    bf16* dst = lds + (s * 2 + kk) * IH + tid * 8;
#pragma unroll
    for (int i = 0; i < 2; ++i)
      async16(gA[i] + kt * 64 + kk * 32, dst + i * 2048);
  };
  auto stB = [&](int kt, int s, int kk) {
    bf16* dst = lds + 4 * IH + (s * 2 + kk) * IH + tid * 8;
#pragma unroll
    for (int i = 0; i < 2; ++i)
      async16(gB[i] + kt * 64 + kk * 32, dst + i * 2048);
  };

  // read offsets: frag (mt): lrow = mt*16 + r, slot = ((half<<2)+quad)^(r&7)
  const int aoff = r * 64 + (((wm << 2) + quad) ^ (r & 7)) * 8;
  const int boff = r * 64 + (((wn << 2) + quad) ^ (r & 7)) * 8;

  bf16x8 a[4], b[4];

#define LDA(S, KK) do { const bf16* _p = lds + ((S) * 2 + (KK)) * IH + aoff; \
  _Pragma("unroll") for (int m2 = 0; m2 < 4; ++m2) a[m2] = *(const bf16x8*)(_p + m2 * 1024); } while (0)
#define LDB(S, KK) do { const bf16* _p = lds + 4 * IH + ((S) * 2 + (KK)) * IH + boff; \
  _Pragma("unroll") for (int n2 = 0; n2 < 4; ++n2) b[n2] = *(const bf16x8*)(_p + n2 * 1024); } while (0)
#define MM() do { __builtin_amdgcn_s_setprio(1); \
  _Pragma("unroll") for (int m2 = 0; m2 < 4; ++m2) \
    _Pragma("unroll") for (int n2 = 0; n2 < 4; ++n2) \
      acc[m2][n2] = MFMA16(a[m2], b[n2], acc[m2][n2]); \
  __builtin_amdgcn_s_setprio(0); } while (0)
#define BAR() asm volatile("s_barrier" ::: "memory")

  // prologue: tile0 complete + tile1's kk0; certify tile0 (vmcnt(4) leaves
  // exactly the 4 t1-kk0 loads in flight)
  stA(0, 0, 0); stB(0, 0, 0); stA(0, 0, 1); stB(0, 0, 1);
  stA(1, 1, 0); stB(1, 1, 0);
  asm volatile("s_waitcnt vmcnt(4)" ::: "memory"); BAR();

  for (int t = 0; t < NT; ++t) {
    const int s = t & 1;
    // Phase A (kk0) + stage next tile's kk1
    LDA(s, 0); LDB(s, 0);
    if (t + 1 < NT) { stA(t + 1, s ^ 1, 1); stB(t + 1, s ^ 1, 1); }
    BAR(); MM(); BAR();
    // Phase B (kk1) + stage tile t+2's kk0
    LDA(s, 1); LDB(s, 1);
    if (t + 2 < NT) { stA(t + 2, s, 0); stB(t + 2, s, 0); }
    BAR(); MM();
    // gate: certify tile t+1's four halves. Counted only while S_B(t) was
    // issued; otherwise FULL drain (tail-race fix, see header comment).
    if (t + 2 < NT) asm volatile("s_waitcnt vmcnt(4)" ::: "memory");
    else            asm volatile("s_waitcnt vmcnt(0)" ::: "memory");
    BAR();
  }

#undef LDA
#undef LDB
#undef MM
#undef BAR
}

// ---- epilogues (wave tile 64x64: row base wm*64, col base wn*64) -----------
template<bool CF32>
__device__ __forceinline__
void epi_plain(const floatx4 (&acc)[4][4], void* C, int N, int m0, int n0,
               int wm, int wn, int r, int quad)
{
#pragma unroll
  for (int mt = 0; mt < 4; ++mt) {
#pragma unroll
    for (int nt = 0; nt < 4; ++nt) {
      const int row = m0 + wm * 64 + mt * 16 + quad * 4;
      const int col = n0 + wn * 64 + nt * 16 + r;
#pragma unroll
      for (int g = 0; g < 4; ++g) {
        const size_t ci = (size_t)(row + g) * N + col;
        if constexpr (CF32) ((float*)C)[ci] = acc[mt][nt][g];
        else                ((bf16*)C)[ci]  = (bf16)acc[mt][nt][g];
      }
    }
  }
}

// K path: fused RMSNorm (f32 acc) + RoPE, store bf16 to k_ws [token][h*64+d].
__device__ __forceinline__
void epi_k(const floatx4 (&acc)[4][4], bf16* kws, const float* kw,
           const float* cp, const float* sp, int m0, int n0,
           int wm, int wn, int r, int quad)
{
  const int h = (n0 >> 6) + wn;                    // 0..7
  const float w0 = kw[r], w1 = kw[16 + r], w2 = kw[32 + r], w3 = kw[48 + r];
#pragma unroll
  for (int mt = 0; mt < 4; ++mt) {
#pragma unroll
    for (int g = 0; g < 4; ++g) {
      const int row = m0 + wm * 64 + mt * 16 + quad * 4 + g;
      const float x0 = acc[mt][0][g], x1 = acc[mt][1][g];
      const float x2 = acc[mt][2][g], x3 = acc[mt][3][g];
      float ss = x0 * x0 + x1 * x1 + x2 * x2 + x3 * x3;
      ss += __shfl_xor(ss, 1); ss += __shfl_xor(ss, 2);
      ss += __shfl_xor(ss, 4); ss += __shfl_xor(ss, 8);
      const float rr = rsqrtf(ss * (1.0f / 64.0f) + 1e-6f);
      const float y0 = x0 * rr * w0, y1 = x1 * rr * w1;
      const float y2 = x2 * rr * w2, y3 = x3 * rr * w3;
      const float* cb = cp + (size_t)row * 64 + r;
      const float* sb = sp + (size_t)row * 64 + r;
      bf16* p = kws + (size_t)row * 512 + h * 64 + r;
      p[0]  = (bf16)(y0 * cb[0]  - y2 * sb[0]);
      p[16] = (bf16)(y1 * cb[16] - y3 * sb[16]);
      p[32] = (bf16)(y2 * cb[32] + y0 * sb[32]);
      p[48] = (bf16)(y3 * cb[48] + y1 * sb[48]);
    }
  }
}

// V path: store transposed directly into vt [((b*8+kvh)*64+d)*2048 + s].
__device__ __forceinline__
void epi_v(const floatx4 (&acc)[4][4], bf16* vt, int m0, int n0,
           int wm, int wn, int r, int quad)
{
  const int kvh = (n0 >> 6) + wn;                  // 0..7
  const int b   = m0 >> 11;
  const int sb  = (m0 & 2047) + wm * 64 + quad * 4;
#pragma unroll
  for (int mt = 0; mt < 4; ++mt) {
#pragma unroll
    for (int nt = 0; nt < 4; ++nt) {
      const int d = nt * 16 + r;
      bf16x4 pk;
#pragma unroll
      for (int g = 0; g < 4; ++g) pk[g] = (bf16)acc[mt][nt][g];
      *(bf16x4*)(vt + ((size_t)((b * 8 + kvh) * 64 + d)) * Sc + sb + mt * 16) = pk;
    }
  }
}

__global__ __launch_bounds__(256, 2)
void qkv_gemm8(const bf16* __restrict__ hs,
               const bf16* __restrict__ Wq, const bf16* __restrict__ Wk,
               const bf16* __restrict__ Wv,
               bf16* __restrict__ q_ws, bf16* __restrict__ k_ws,
               bf16* __restrict__ vt_ws,
               const float* __restrict__ kw, const float* __restrict__ cp,
               const float* __restrict__ sp)
{
  __shared__ bf16 lds[8 * 128 * 32];               // 64 KiB -> 2 blocks/CU
  const int wg  = blockIdx.x;
  const int swz = (wg & 7) * 96 + (wg >> 3);       // 768 blocks, bijective
  const int mi  = swz / 24, ni = swz % 24;
  const bf16* Bw; int n0;
  if (ni < 16)      { Bw = Wq; n0 = ni * 128; }
  else if (ni < 20) { Bw = Wk; n0 = (ni - 16) * 128; }
  else              { Bw = Wv; n0 = (ni - 20) * 128; }

  floatx4 acc[4][4] = {};
  gemm128_core(hs, Bw, HIDc, mi * 128, n0, lds, acc);

  const int lane = threadIdx.x & 63, w = threadIdx.x >> 6;
  const int r = lane & 15, quad = lane >> 4;
  const int wm = w >> 1, wn = w & 1;
  if (ni < 16)
    epi_plain<false>(acc, q_ws, 2048, mi * 128, n0, wm, wn, r, quad);
  else if (ni < 20)
    epi_k(acc, k_ws, kw, cp, sp, mi * 128, n0, wm, wn, r, quad);
  else
    epi_v(acc, vt_ws, mi * 128, n0, wm, wn, r, quad);
}

__global__ __launch_bounds__(256, 2)
void o_gemm8(const bf16* __restrict__ a_ws, const bf16* __restrict__ Wo,
             float* __restrict__ out)
{
  __shared__ bf16 lds[8 * 128 * 32];               // 64 KiB -> 2 blocks/CU
  const int wg  = blockIdx.x;
  const int swz = (wg & 7) * 64 + (wg >> 3);       // 512 blocks, bijective
  const int mi  = swz >> 4, ni = swz & 15;

  floatx4 acc[4][4] = {};
  gemm128_core(a_ws, Wo, NHc * HDc, mi * 128, ni * 128, lds, acc);

  const int lane = threadIdx.x & 63, w = threadIdx.x >> 6;
  const int r = lane & 15, quad = lane >> 4;
  const int wm = w >> 1, wn = w & 1;
  epi_plain<true>(acc, out, HIDc, mi * 128, ni * 128, wm, wn, r, quad);
}

// ---------------------------------------------------------------------------
// Causal flash attention, GQA groups=4, fused Q RMSNorm+RoPE, static-max
// softmax (scores*scale in [-8,8]; m=9 fixed, l reduced once at end).
// Block = (b, h, pa) handling q-tiles {31-pa, pa}: constant 33 tile-steps.
// Round-1-verified structure: single-buffer K/V^T staging, {sync; stage(j);
// sync; compute(j)} ordering, 1024 blocks, launch_bounds(256,4).
// K/V^T staged via async global->LDS with XOR swizzle applied to the GLOBAL
// address. Diagonal-only mask path; setprio around MFMA clusters.
// o aliases q (each block reads/writes only its own exclusive Q region).
// ---------------------------------------------------------------------------
__global__ __launch_bounds__(256, 4)
void attn_fwd(const bf16* __restrict__ q, const bf16* __restrict__ k,
              const bf16* __restrict__ vt, bf16* __restrict__ o,
              const float* __restrict__ qw, const float* __restrict__ cp,
              const float* __restrict__ sp)
{
  __shared__ bf16 Ks[64 * 64];
  __shared__ bf16 Vs[64 * 64];        // V^T [d][kv], swizzled
  __shared__ bf16 Ps[4][16 * 72];     // per-wave P round-trip, stride 72

  const int bi  = blockIdx.x;
  const int pa  = bi & 15;
  const int h   = (bi >> 4) & 31;
  const int b   = bi >> 9;
  const int kvh = h >> 2;
  const int tid = threadIdx.x, lane = tid & 63, w = tid >> 6;
  const int r = lane & 15, quad = lane >> 4;
  const int qt0 = 31 - pa, qt1 = pa;   // heavy tile first (active all iters)

  // Q load + fused RMSNorm (kScale folded in) + RoPE
  const floatx8 w0 = *(const floatx8*)(qw + quad * 8);
  const floatx8 w1 = *(const floatx8*)(qw + 32 + quad * 8);
  bf16x8 qf[2][2];
#pragma unroll
  for (int t = 0; t < 2; ++t) {
    const int qt = t == 0 ? qt0 : qt1;
    const int m = b * Sc + qt * 64 + w * 16 + r;
    const bf16* qp = q + (size_t)m * (NHc * HDc) + h * HDc + quad * 8;
    bf16x8 x0 = *(const bf16x8*)qp;
    bf16x8 x1 = *(const bf16x8*)(qp + 32);
    float ss = 0.f;
#pragma unroll
    for (int i = 0; i < 8; ++i)
      ss += (float)x0[i] * (float)x0[i] + (float)x1[i] * (float)x1[i];
    ss += __shfl_xor(ss, 16);
    ss += __shfl_xor(ss, 32);
    const float rq = rsqrtf(ss * (1.0f / 64.0f) + 1e-6f) * kScale;
    const floatx8 c0 = *(const floatx8*)(cp + (size_t)m * 64 + quad * 8);
    const floatx8 c1 = *(const floatx8*)(cp + (size_t)m * 64 + 32 + quad * 8);
    const floatx8 s0 = *(const floatx8*)(sp + (size_t)m * 64 + quad * 8);
    const floatx8 s1 = *(const floatx8*)(sp + (size_t)m * 64 + 32 + quad * 8);
    bf16x8 y0v, y1v;
#pragma unroll
    for (int i = 0; i < 8; ++i) {
      const float y0 = (float)x0[i] * rq * w0[i];
      const float y1 = (float)x1[i] * rq * w1[i];
      y0v[i] = (bf16)(y0 * c0[i] - y1 * s0[i]);   // d < 32
      y1v[i] = (bf16)(y1 * c1[i] + y0 * s1[i]);   // d >= 32
    }
    qf[t][0] = y0v; qf[t][1] = y1v;
  }

  floatx4 accO[2][4] = {};
  float lsum[2][4] = {};

  const int kvr = tid >> 3;            // staging row (0..31), +32 for seg1
  const int cx  = ((tid & 7) * 8) ^ (8 * (kvr & 7));  // swizzle on GLOBAL side
  const int xk  = 8 * (r & 7);                        // read-side XOR

  const bf16* kp = k + (size_t)b * Sc * (NKVc * HDc) + kvh * HDc;
  const bf16* vp = vt + ((size_t)((b * NKVc + kvh) * 64)) * Sc;

  for (int j = 0; j <= qt0; ++j) {
    __syncthreads();                 // prior tile's fragment reads done (WAR)
    {
      const bf16* kj = kp + (size_t)j * 64 * (NKVc * HDc);
      const bf16* vj = vp + j * 64;
      async16(kj + (size_t)kvr * (NKVc * HDc) + cx, Ks + tid * 8);
      async16(kj + (size_t)(kvr + 32) * (NKVc * HDc) + cx, Ks + (tid + 256) * 8);
      async16(vj + (size_t)kvr * Sc + cx, Vs + tid * 8);
      async16(vj + (size_t)(kvr + 32) * Sc + cx, Vs + (tid + 256) * 8);
    }
    __syncthreads();                 // drain async loads

#pragma unroll
    for (int t = 0; t < 2; ++t) {
      if (t == 1 && j > qt1) continue;          // light tile finished
      const int qt = t == 0 ? qt0 : qt1;

      // S = Q K^T (16 x 64 per wave), pre-scaled
      floatx4 sa[4];
#pragma unroll
      for (int nt = 0; nt < 4; ++nt) sa[nt] = floatx4{0.f, 0.f, 0.f, 0.f};
      __builtin_amdgcn_s_setprio(1);
#pragma unroll
      for (int nt = 0; nt < 4; ++nt) {
        const int kv = nt * 16 + r;
        const bf16x8 kb0 = *(const bf16x8*)(&Ks[kv * 64 + ((quad * 8) ^ xk)]);
        const bf16x8 kb1 = *(const bf16x8*)(&Ks[kv * 64 + ((quad * 8 + 32) ^ xk)]);
        sa[nt] = MFMA16(qf[t][0], kb0, sa[nt]);
        sa[nt] = MFMA16(qf[t][1], kb1, sa[nt]);
      }
      __builtin_amdgcn_s_setprio(0);

      // static-max softmax; mask path only on the diagonal tile
      if (j != qt) {
#pragma unroll
        for (int g = 0; g < 4; ++g)
#pragma unroll
          for (int nt = 0; nt < 4; ++nt) {
            const float p = __expf(sa[nt][g] - kMax);
            lsum[t][g] += p;
            Ps[w][(quad * 4 + g) * 72 + nt * 16 + r] = (bf16)p;
          }
      } else {
        const int maskbase = w * 16 + quad * 4;
#pragma unroll
        for (int g = 0; g < 4; ++g)
#pragma unroll
          for (int nt = 0; nt < 4; ++nt) {
            const float p = (nt * 16 + r <= maskbase + g)
                                ? __expf(sa[nt][g] - kMax) : 0.f;
            lsum[t][g] += p;
            Ps[w][(quad * 4 + g) * 72 + nt * 16 + r] = (bf16)p;
          }
      }

      const bf16x8 pa0 = *(const bf16x8*)(&Ps[w][r * 72 + quad * 8]);
      const bf16x8 pa1 = *(const bf16x8*)(&Ps[w][r * 72 + 32 + quad * 8]);
      __builtin_amdgcn_s_setprio(1);
#pragma unroll
      for (int dt = 0; dt < 4; ++dt) {
        const int d = dt * 16 + r;
        const bf16x8 vb0 = *(const bf16x8*)(&Vs[d * 64 + ((quad * 8) ^ xk)]);
        const bf16x8 vb1 = *(const bf16x8*)(&Vs[d * 64 + ((quad * 8 + 32) ^ xk)]);
        accO[t][dt] = MFMA16(pa0, vb0, accO[t][dt]);
        accO[t][dt] = MFMA16(pa1, vb1, accO[t][dt]);
      }
      __builtin_amdgcn_s_setprio(0);
    }
  }

  // epilogue: reduce l across the 16 column-lanes, divide, write
#pragma unroll
  for (int t = 0; t < 2; ++t) {
    const int qt = t == 0 ? qt0 : qt1;
#pragma unroll
    for (int reg = 0; reg < 4; ++reg) {
      float l = lsum[t][reg];
#pragma unroll
      for (int off = 1; off < 16; off <<= 1) l += __shfl_xor(l, off);
      const float inv = 1.0f / l;
      const size_t row = (size_t)(b * Sc + qt * 64 + w * 16 + quad * 4 + reg);
#pragma unroll
      for (int dt = 0; dt < 4; ++dt)
        o[row * (NHc * HDc) + h * HDc + dt * 16 + r] = (bf16)(accO[t][dt][reg] * inv);
    }
  }
}

// ---------------------------------------------------------------------------
extern "C" void kernel_launch(void* const* d_in, const int* in_sizes, int n_in,
                              void* d_out, int out_size, void* d_ws, size_t ws_size,
                              hipStream_t stream)
{
  const float* hs = (const float*)d_in[0];
  const float* cp = (const float*)d_in[1];
  const float* sp = (const float*)d_in[2];
  const float* Wq = (const float*)d_in[3];
  const float* Wk = (const float*)d_in[4];
  const float* Wv = (const float*)d_in[5];
  const float* Wo = (const float*)d_in[6];
  const float* qw = (const float*)d_in[7];
  const float* kw = (const float*)d_in[8];
  float* out = (float*)d_out;

  char* ws = (char*)d_ws;
  bf16* q_ws  = (bf16*)ws;                      // 16 MiB
  bf16* k_ws  = (bf16*)(ws + (16u << 20));      // 4 MiB
  bf16* vt_ws = (bf16*)(ws + (24u << 20));      // 4 MiB
  bf16* hs_b  = (bf16*)(ws + (28u << 20));      // 16 MiB
  bf16* Wq_b  = (bf16*)(ws + (44u << 20));      // 8 MiB
  bf16* Wk_b  = (bf16*)(ws + (52u << 20));      // 2 MiB
  bf16* Wv_b  = (bf16*)(ws + (54u << 20));      // 2 MiB
  bf16* Wo_b  = (bf16*)(ws + (56u << 20));      // 8 MiB -> 64 MiB total
  bf16* a_ws  = q_ws;                           // safe alias (see attn_fwd)

  dim3 blk(256);
  cvt5<<<dim3(256, 5), blk, 0, stream>>>(
      hs, hs_b, 4096 * 2048, Wq, Wq_b, 2048 * 2048, Wk, Wk_b, 512 * 2048,
      Wv, Wv_b, 512 * 2048, Wo, Wo_b, 2048 * 2048);
  qkv_gemm8<<<dim3(768), blk, 0, stream>>>(hs_b, Wq_b, Wk_b, Wv_b,
                                           q_ws, k_ws, vt_ws, kw, cp, sp);
  attn_fwd<<<dim3(1024), blk, 0, stream>>>(q_ws, k_ws, vt_ws, a_ws, qw, cp, sp);
  o_gemm8<<<dim3(512), blk, 0, stream>>>(a_ws, Wo_b, out);
}

// Round 12
// 296.406 us; speedup vs baseline: 1.0089x; 1.0089x over previous
//
#include <hip/hip_runtime.h>
#include <hip/hip_bf16.h>
#include <stdint.h>

typedef __bf16 bf16;
typedef __bf16 bf16x4 __attribute__((ext_vector_type(4)));
typedef __bf16 bf16x8 __attribute__((ext_vector_type(8)));
typedef float floatx4 __attribute__((ext_vector_type(4)));
typedef float floatx8 __attribute__((ext_vector_type(8)));

#define MFMA16(A, B, C) __builtin_amdgcn_mfma_f32_16x16x32_bf16(A, B, C, 0, 0, 0)

constexpr int Sc = 2048, HIDc = 2048, NHc = 32, NKVc = 8, HDc = 64;
constexpr float kScale = 0.125f;   // HD^-0.5
constexpr float kMax = 9.0f;       // static softmax max: |s*scale| <= 8 (|q|=|k|=8)

// async 16B global -> LDS (wave-uniform base + lane*16 on the LDS side)
__device__ __forceinline__ void async16(const bf16* g, bf16* l) {
  __builtin_amdgcn_global_load_lds(
      (const __attribute__((address_space(1))) void*)g,
      (__attribute__((address_space(3))) void*)l, 16, 0, 0);
}

// ---------------------------------------------------------------------------
// f32 -> bf16 conversion for hs + 4 weight matrices (blockIdx.y selects).
// ---------------------------------------------------------------------------
__global__ __launch_bounds__(256)
void cvt5(const float* __restrict__ s0, bf16* __restrict__ d0, int n0,
          const float* __restrict__ s1, bf16* __restrict__ d1, int n1,
          const float* __restrict__ s2, bf16* __restrict__ d2, int n2,
          const float* __restrict__ s3, bf16* __restrict__ d3, int n3,
          const float* __restrict__ s4, bf16* __restrict__ d4, int n4)
{
  const float* s; bf16* d; int n;
  switch (blockIdx.y) {
    case 0: s = s0; d = d0; n = n0; break;
    case 1: s = s1; d = d1; n = n1; break;
    case 2: s = s2; d = d2; n = n2; break;
    case 3: s = s3; d = d3; n = n3; break;
    default: s = s4; d = d4; n = n4; break;
  }
  const size_t stride = (size_t)gridDim.x * blockDim.x * 8;
  for (size_t i = ((size_t)blockIdx.x * blockDim.x + threadIdx.x) * 8;
       i < (size_t)n; i += stride) {
    floatx8 f = *(const floatx8*)(s + i);
    bf16x8 o;
#pragma unroll
    for (int j = 0; j < 8; ++j) o[j] = (bf16)f[j];
    *(bf16x8*)(d + i) = o;
  }
}

// ---------------------------------------------------------------------------
// 128x128 pipelined GEMM core, 256 threads / 4 waves (2x2, 64x64 per wave).
// C(128x128) = A(128xK) @ Bw(NxK)^T slice, bf16 in, fp32 accum. BK=64 as two
// K-half images of 8 KB each; LDS = 2buf x 2half x (A,B) = 64 KiB
// -> 2 blocks/CU resident (cross-block TLP covers the ds_read drains).
// Packed LDS rows: 128B row = M-halves (lrow, lrow+64) as 16B slots 0-3/4-7,
// slot XOR (lrow&7), involution pre-applied to the GLOBAL source address
// (linear LDS dest for global_load_lds). Conflicts measured 0 (round 6).
// Schedule per K-tile: {phA: read kk0 frags, stage t+1 kk1; BAR; 16 MFMA;
// BAR; phB: read kk1, stage t+2 kk0; BAR; 16 MFMA; gate; BAR}.
// TAIL-RACE FIX (r9 post-mortem, verified r10): when phase B skips its stage
// (t+2 >= NT), vmcnt(4) would leave tile t+1's kk1 uncertified; gate is
// vmcnt(4) only while a phase-B stage was issued this iteration, else
// vmcnt(0) (full drain on the final two gates only).
// ---------------------------------------------------------------------------
__device__ __forceinline__
void gemm128_core(const bf16* __restrict__ A, const bf16* __restrict__ Bw,
                  int K, int m0, int n0, bf16* __restrict__ lds,
                  floatx4 (&acc)[4][4])
{
  constexpr int IH = 128 * 32;      // elements per K-half image (8 KB)

  const int tid  = threadIdx.x;     // 0..255
  const int lane = tid & 63;
  const int w    = tid >> 6;        // 0..3
  const int r    = lane & 15;
  const int quad = lane >> 4;
  const int wm   = w >> 1;          // 2 wave rows
  const int wn   = w & 1;           // 2 wave cols
  const int NT   = K >> 6;

  // staging sources, pre-swizzled: chunk ch=(i*256+tid) -> lrow=ch>>3 (0..63),
  // global slot sl=(ch&7)^(lrow&7); sl>>2 = M-half, sl&3 = 16B K-granule.
  const bf16* gA[2]; const bf16* gB[2];
#pragma unroll
  for (int i = 0; i < 2; ++i) {
    const int ch = i * 256 + tid;
    const int lrow = ch >> 3, sl = (ch & 7) ^ (lrow & 7);
    gA[i] = A  + (size_t)(m0 + (sl >> 2) * 64 + lrow) * K + (sl & 3) * 8;
    gB[i] = Bw + (size_t)(n0 + (sl >> 2) * 64 + lrow) * K + (sl & 3) * 8;
  }

  auto stA = [&](int kt, int s, int kk) {
    bf16* dst = lds + (s * 2 + kk) * IH + tid * 8;
#pragma unroll
    for (int i = 0; i < 2; ++i)
      async16(gA[i] + kt * 64 + kk * 32, dst + i * 2048);
  };
  auto stB = [&](int kt, int s, int kk) {
    bf16* dst = lds + 4 * IH + (s * 2 + kk) * IH + tid * 8;
#pragma unroll
    for (int i = 0; i < 2; ++i)
      async16(gB[i] + kt * 64 + kk * 32, dst + i * 2048);
  };

  // read offsets: frag (mt): lrow = mt*16 + r, slot = ((half<<2)+quad)^(r&7)
  const int aoff = r * 64 + (((wm << 2) + quad) ^ (r & 7)) * 8;
  const int boff = r * 64 + (((wn << 2) + quad) ^ (r & 7)) * 8;

  bf16x8 a[4], b[4];

#define LDA(S, KK) do { const bf16* _p = lds + ((S) * 2 + (KK)) * IH + aoff; \
  _Pragma("unroll") for (int m2 = 0; m2 < 4; ++m2) a[m2] = *(const bf16x8*)(_p + m2 * 1024); } while (0)
#define LDB(S, KK) do { const bf16* _p = lds + 4 * IH + ((S) * 2 + (KK)) * IH + boff; \
  _Pragma("unroll") for (int n2 = 0; n2 < 4; ++n2) b[n2] = *(const bf16x8*)(_p + n2 * 1024); } while (0)
#define MM() do { __builtin_amdgcn_s_setprio(1); \
  _Pragma("unroll") for (int m2 = 0; m2 < 4; ++m2) \
    _Pragma("unroll") for (int n2 = 0; n2 < 4; ++n2) \
      acc[m2][n2] = MFMA16(a[m2], b[n2], acc[m2][n2]); \
  __builtin_amdgcn_s_setprio(0); } while (0)
#define BAR() asm volatile("s_barrier" ::: "memory")

  // prologue: tile0 complete + tile1's kk0; certify tile0 (vmcnt(4) leaves
  // exactly the 4 t1-kk0 loads in flight)
  stA(0, 0, 0); stB(0, 0, 0); stA(0, 0, 1); stB(0, 0, 1);
  stA(1, 1, 0); stB(1, 1, 0);
  asm volatile("s_waitcnt vmcnt(4)" ::: "memory"); BAR();

  for (int t = 0; t < NT; ++t) {
    const int s = t & 1;
    // Phase A (kk0) + stage next tile's kk1
    LDA(s, 0); LDB(s, 0);
    if (t + 1 < NT) { stA(t + 1, s ^ 1, 1); stB(t + 1, s ^ 1, 1); }
    BAR(); MM(); BAR();
    // Phase B (kk1) + stage tile t+2's kk0
    LDA(s, 1); LDB(s, 1);
    if (t + 2 < NT) { stA(t + 2, s, 0); stB(t + 2, s, 0); }
    BAR(); MM();
    // gate: certify tile t+1's four halves. Counted only while S_B(t) was
    // issued; otherwise FULL drain (tail-race fix, see header comment).
    if (t + 2 < NT) asm volatile("s_waitcnt vmcnt(4)" ::: "memory");
    else            asm volatile("s_waitcnt vmcnt(0)" ::: "memory");
    BAR();
  }

#undef LDA
#undef LDB
#undef MM
#undef BAR
}

// ---- epilogues (wave tile 64x64: row base wm*64, col base wn*64) -----------
template<bool CF32>
__device__ __forceinline__
void epi_plain(const floatx4 (&acc)[4][4], void* C, int N, int m0, int n0,
               int wm, int wn, int r, int quad)
{
#pragma unroll
  for (int mt = 0; mt < 4; ++mt) {
#pragma unroll
    for (int nt = 0; nt < 4; ++nt) {
      const int row = m0 + wm * 64 + mt * 16 + quad * 4;
      const int col = n0 + wn * 64 + nt * 16 + r;
#pragma unroll
      for (int g = 0; g < 4; ++g) {
        const size_t ci = (size_t)(row + g) * N + col;
        if constexpr (CF32) ((float*)C)[ci] = acc[mt][nt][g];
        else                ((bf16*)C)[ci]  = (bf16)acc[mt][nt][g];
      }
    }
  }
}

// K path: fused RMSNorm (f32 acc) + RoPE, store bf16 to k_ws [token][h*64+d].
__device__ __forceinline__
void epi_k(const floatx4 (&acc)[4][4], bf16* kws, const float* kw,
           const float* cp, const float* sp, int m0, int n0,
           int wm, int wn, int r, int quad)
{
  const int h = (n0 >> 6) + wn;                    // 0..7
  const float w0 = kw[r], w1 = kw[16 + r], w2 = kw[32 + r], w3 = kw[48 + r];
#pragma unroll
  for (int mt = 0; mt < 4; ++mt) {
#pragma unroll
    for (int g = 0; g < 4; ++g) {
      const int row = m0 + wm * 64 + mt * 16 + quad * 4 + g;
      const float x0 = acc[mt][0][g], x1 = acc[mt][1][g];
      const float x2 = acc[mt][2][g], x3 = acc[mt][3][g];
      float ss = x0 * x0 + x1 * x1 + x2 * x2 + x3 * x3;
      ss += __shfl_xor(ss, 1); ss += __shfl_xor(ss, 2);
      ss += __shfl_xor(ss, 4); ss += __shfl_xor(ss, 8);
      const float rr = rsqrtf(ss * (1.0f / 64.0f) + 1e-6f);
      const float y0 = x0 * rr * w0, y1 = x1 * rr * w1;
      const float y2 = x2 * rr * w2, y3 = x3 * rr * w3;
      const float* cb = cp + (size_t)row * 64 + r;
      const float* sb = sp + (size_t)row * 64 + r;
      bf16* p = kws + (size_t)row * 512 + h * 64 + r;
      p[0]  = (bf16)(y0 * cb[0]  - y2 * sb[0]);
      p[16] = (bf16)(y1 * cb[16] - y3 * sb[16]);
      p[32] = (bf16)(y2 * cb[32] + y0 * sb[32]);
      p[48] = (bf16)(y3 * cb[48] + y1 * sb[48]);
    }
  }
}

// V path: store transposed directly into vt [((b*8+kvh)*64+d)*2048 + s].
__device__ __forceinline__
void epi_v(const floatx4 (&acc)[4][4], bf16* vt, int m0, int n0,
           int wm, int wn, int r, int quad)
{
  const int kvh = (n0 >> 6) + wn;                  // 0..7
  const int b   = m0 >> 11;
  const int sb  = (m0 & 2047) + wm * 64 + quad * 4;
#pragma unroll
  for (int mt = 0; mt < 4; ++mt) {
#pragma unroll
    for (int nt = 0; nt < 4; ++nt) {
      const int d = nt * 16 + r;
      bf16x4 pk;
#pragma unroll
      for (int g = 0; g < 4; ++g) pk[g] = (bf16)acc[mt][nt][g];
      *(bf16x4*)(vt + ((size_t)((b * 8 + kvh) * 64 + d)) * Sc + sb + mt * 16) = pk;
    }
  }
}

__global__ __launch_bounds__(256, 2)
void qkv_gemm8(const bf16* __restrict__ hs,
               const bf16* __restrict__ Wq, const bf16* __restrict__ Wk,
               const bf16* __restrict__ Wv,
               bf16* __restrict__ q_ws, bf16* __restrict__ k_ws,
               bf16* __restrict__ vt_ws,
               const float* __restrict__ kw, const float* __restrict__ cp,
               const float* __restrict__ sp)
{
  __shared__ bf16 lds[8 * 128 * 32];               // 64 KiB -> 2 blocks/CU
  const int wg  = blockIdx.x;
  const int swz = (wg & 7) * 96 + (wg >> 3);       // 768 blocks, bijective
  const int mi  = swz / 24, ni = swz % 24;
  const bf16* Bw; int n0;
  if (ni < 16)      { Bw = Wq; n0 = ni * 128; }
  else if (ni < 20) { Bw = Wk; n0 = (ni - 16) * 128; }
  else              { Bw = Wv; n0 = (ni - 20) * 128; }

  floatx4 acc[4][4] = {};
  gemm128_core(hs, Bw, HIDc, mi * 128, n0, lds, acc);

  const int lane = threadIdx.x & 63, w = threadIdx.x >> 6;
  const int r = lane & 15, quad = lane >> 4;
  const int wm = w >> 1, wn = w & 1;
  if (ni < 16)
    epi_plain<false>(acc, q_ws, 2048, mi * 128, n0, wm, wn, r, quad);
  else if (ni < 20)
    epi_k(acc, k_ws, kw, cp, sp, mi * 128, n0, wm, wn, r, quad);
  else
    epi_v(acc, vt_ws, mi * 128, n0, wm, wn, r, quad);
}

__global__ __launch_bounds__(256, 2)
void o_gemm8(const bf16* __restrict__ a_ws, const bf16* __restrict__ Wo,
             float* __restrict__ out)
{
  __shared__ bf16 lds[8 * 128 * 32];               // 64 KiB -> 2 blocks/CU
  const int wg  = blockIdx.x;
  const int swz = (wg & 7) * 64 + (wg >> 3);       // 512 blocks, bijective
  const int mi  = swz >> 4, ni = swz & 15;

  floatx4 acc[4][4] = {};
  gemm128_core(a_ws, Wo, NHc * HDc, mi * 128, ni * 128, lds, acc);

  const int lane = threadIdx.x & 63, w = threadIdx.x >> 6;
  const int r = lane & 15, quad = lane >> 4;
  const int wm = w >> 1, wn = w & 1;
  epi_plain<true>(acc, out, HIDc, mi * 128, ni * 128, wm, wn, r, quad);
}

// ---------------------------------------------------------------------------
// Causal flash attention, GQA groups=4, fused Q RMSNorm+RoPE, static-max
// softmax (scores*scale in [-8,8]; m=9 fixed, l reduced once at end).
// ONE q-tile per block (2048 blocks, heavy tiles dispatched first via
// qt = 31 - bi/64) -> 6 blocks/CU resident (LDS 25600, launch_bounds(256,6))
// vs 4 with the old paired-1024 grid: cross-block TLP is the latency hider
// (r2: intra-block dbuf loses to it). Inner loop ordering {sync; stage(j);
// sync; compute(j)} is byte-identical to the 5x-harness-verified r1 pattern
// (r3's failure used a ROTATED loop + pre-prologue stage; not repeated here).
// K/V^T staged via async global->LDS with XOR swizzle applied to the GLOBAL
// address. Diagonal-only mask path; setprio around MFMA clusters.
// o aliases q: each block reads/writes only its own exclusive (row,col)
// region (rows qt*64.., cols h*64..) -- disjoint across blocks.
// ---------------------------------------------------------------------------
__global__ __launch_bounds__(256, 6)
void attn_fwd(const bf16* __restrict__ q, const bf16* __restrict__ k,
              const bf16* __restrict__ vt, bf16* __restrict__ o,
              const float* __restrict__ qw, const float* __restrict__ cp,
              const float* __restrict__ sp)
{
  __shared__ bf16 Ks[64 * 64];
  __shared__ bf16 Vs[64 * 64];        // V^T [d][kv], swizzled
  __shared__ bf16 Ps[4][16 * 72];     // per-wave P round-trip, stride 72

  const int bi  = blockIdx.x;          // 0..2047
  const int qt  = 31 - (bi >> 6);      // heavy q-tiles first in dispatch order
  const int hb  = bi & 63;
  const int h   = hb & 31;
  const int b   = hb >> 5;
  const int kvh = h >> 2;
  const int tid = threadIdx.x, lane = tid & 63, w = tid >> 6;
  const int r = lane & 15, quad = lane >> 4;

  // Q load + fused RMSNorm (kScale folded in) + RoPE -- single tile
  const floatx8 w0 = *(const floatx8*)(qw + quad * 8);
  const floatx8 w1 = *(const floatx8*)(qw + 32 + quad * 8);
  bf16x8 qf0, qf1;
  {
    const int m = b * Sc + qt * 64 + w * 16 + r;
    const bf16* qp = q + (size_t)m * (NHc * HDc) + h * HDc + quad * 8;
    bf16x8 x0 = *(const bf16x8*)qp;
    bf16x8 x1 = *(const bf16x8*)(qp + 32);
    float ss = 0.f;
#pragma unroll
    for (int i = 0; i < 8; ++i)
      ss += (float)x0[i] * (float)x0[i] + (float)x1[i] * (float)x1[i];
    ss += __shfl_xor(ss, 16);
    ss += __shfl_xor(ss, 32);
    const float rq = rsqrtf(ss * (1.0f / 64.0f) + 1e-6f) * kScale;
    const floatx8 c0 = *(const floatx8*)(cp + (size_t)m * 64 + quad * 8);
    const floatx8 c1 = *(const floatx8*)(cp + (size_t)m * 64 + 32 + quad * 8);
    const floatx8 s0 = *(const floatx8*)(sp + (size_t)m * 64 + quad * 8);
    const floatx8 s1 = *(const floatx8*)(sp + (size_t)m * 64 + 32 + quad * 8);
#pragma unroll
    for (int i = 0; i < 8; ++i) {
      const float y0 = (float)x0[i] * rq * w0[i];
      const float y1 = (float)x1[i] * rq * w1[i];
      qf0[i] = (bf16)(y0 * c0[i] - y1 * s0[i]);   // d < 32
      qf1[i] = (bf16)(y1 * c1[i] + y0 * s1[i]);   // d >= 32
    }
  }

  floatx4 accO[4] = {};
  float lsum[4] = {};

  const int kvr = tid >> 3;            // staging row (0..31), +32 for seg1
  const int cx  = ((tid & 7) * 8) ^ (8 * (kvr & 7));  // swizzle on GLOBAL side
  const int xk  = 8 * (r & 7);                        // read-side XOR

  const bf16* kp = k + (size_t)b * Sc * (NKVc * HDc) + kvh * HDc;
  const bf16* vp = vt + ((size_t)((b * NKVc + kvh) * 64)) * Sc;

  for (int j = 0; j <= qt; ++j) {
    __syncthreads();                 // prior tile's fragment reads done (WAR)
    {
      const bf16* kj = kp + (size_t)j * 64 * (NKVc * HDc);
      const bf16* vj = vp + j * 64;
      async16(kj + (size_t)kvr * (NKVc * HDc) + cx, Ks + tid * 8);
      async16(kj + (size_t)(kvr + 32) * (NKVc * HDc) + cx, Ks + (tid + 256) * 8);
      async16(vj + (size_t)kvr * Sc + cx, Vs + tid * 8);
      async16(vj + (size_t)(kvr + 32) * Sc + cx, Vs + (tid + 256) * 8);
    }
    __syncthreads();                 // drain async loads

    // S = Q K^T (16 x 64 per wave), pre-scaled
    floatx4 sa[4];
#pragma unroll
    for (int nt = 0; nt < 4; ++nt) sa[nt] = floatx4{0.f, 0.f, 0.f, 0.f};
    __builtin_amdgcn_s_setprio(1);
#pragma unroll
    for (int nt = 0; nt < 4; ++nt) {
      const int kv = nt * 16 + r;
      const bf16x8 kb0 = *(const bf16x8*)(&Ks[kv * 64 + ((quad * 8) ^ xk)]);
      const bf16x8 kb1 = *(const bf16x8*)(&Ks[kv * 64 + ((quad * 8 + 32) ^ xk)]);
      sa[nt] = MFMA16(qf0, kb0, sa[nt]);
      sa[nt] = MFMA16(qf1, kb1, sa[nt]);
    }
    __builtin_amdgcn_s_setprio(0);

    // static-max softmax; mask path only on the diagonal tile
    if (j != qt) {
#pragma unroll
      for (int g = 0; g < 4; ++g)
#pragma unroll
        for (int nt = 0; nt < 4; ++nt) {
          const float p = __expf(sa[nt][g] - kMax);
          lsum[g] += p;
          Ps[w][(quad * 4 + g) * 72 + nt * 16 + r] = (bf16)p;
        }
    } else {
      const int maskbase = w * 16 + quad * 4;
#pragma unroll
      for (int g = 0; g < 4; ++g)
#pragma unroll
        for (int nt = 0; nt < 4; ++nt) {
          const float p = (nt * 16 + r <= maskbase + g)
                              ? __expf(sa[nt][g] - kMax) : 0.f;
          lsum[g] += p;
          Ps[w][(quad * 4 + g) * 72 + nt * 16 + r] = (bf16)p;
        }
    }

    const bf16x8 pa0 = *(const bf16x8*)(&Ps[w][r * 72 + quad * 8]);
    const bf16x8 pa1 = *(const bf16x8*)(&Ps[w][r * 72 + 32 + quad * 8]);
    __builtin_amdgcn_s_setprio(1);
#pragma unroll
    for (int dt = 0; dt < 4; ++dt) {
      const int d = dt * 16 + r;
      const bf16x8 vb0 = *(const bf16x8*)(&Vs[d * 64 + ((quad * 8) ^ xk)]);
      const bf16x8 vb1 = *(const bf16x8*)(&Vs[d * 64 + ((quad * 8 + 32) ^ xk)]);
      accO[dt] = MFMA16(pa0, vb0, accO[dt]);
      accO[dt] = MFMA16(pa1, vb1, accO[dt]);
    }
    __builtin_amdgcn_s_setprio(0);
  }

  // epilogue: reduce l across the 16 column-lanes, divide, write
#pragma unroll
  for (int reg = 0; reg < 4; ++reg) {
    float l = lsum[reg];
#pragma unroll
    for (int off = 1; off < 16; off <<= 1) l += __shfl_xor(l, off);
    const float inv = 1.0f / l;
    const size_t row = (size_t)(b * Sc + qt * 64 + w * 16 + quad * 4 + reg);
#pragma unroll
    for (int dt = 0; dt < 4; ++dt)
      o[row * (NHc * HDc) + h * HDc + dt * 16 + r] = (bf16)(accO[dt][reg] * inv);
  }
}

// ---------------------------------------------------------------------------
extern "C" void kernel_launch(void* const* d_in, const int* in_sizes, int n_in,
                              void* d_out, int out_size, void* d_ws, size_t ws_size,
                              hipStream_t stream)
{
  const float* hs = (const float*)d_in[0];
  const float* cp = (const float*)d_in[1];
  const float* sp = (const float*)d_in[2];
  const float* Wq = (const float*)d_in[3];
  const float* Wk = (const float*)d_in[4];
  const float* Wv = (const float*)d_in[5];
  const float* Wo = (const float*)d_in[6];
  const float* qw = (const float*)d_in[7];
  const float* kw = (const float*)d_in[8];
  float* out = (float*)d_out;

  char* ws = (char*)d_ws;
  bf16* q_ws  = (bf16*)ws;                      // 16 MiB
  bf16* k_ws  = (bf16*)(ws + (16u << 20));      // 4 MiB
  bf16* vt_ws = (bf16*)(ws + (24u << 20));      // 4 MiB
  bf16* hs_b  = (bf16*)(ws + (28u << 20));      // 16 MiB
  bf16* Wq_b  = (bf16*)(ws + (44u << 20));      // 8 MiB
  bf16* Wk_b  = (bf16*)(ws + (52u << 20));      // 2 MiB
  bf16* Wv_b  = (bf16*)(ws + (54u << 20));      // 2 MiB
  bf16* Wo_b  = (bf16*)(ws + (56u << 20));      // 8 MiB -> 64 MiB total
  bf16* a_ws  = q_ws;                           // safe alias (see attn_fwd)

  dim3 blk(256);
  cvt5<<<dim3(256, 5), blk, 0, stream>>>(
      hs, hs_b, 4096 * 2048, Wq, Wq_b, 2048 * 2048, Wk, Wk_b, 512 * 2048,
      Wv, Wv_b, 512 * 2048, Wo, Wo_b, 2048 * 2048);
  qkv_gemm8<<<dim3(768), blk, 0, stream>>>(hs_b, Wq_b, Wk_b, Wv_b,
                                           q_ws, k_ws, vt_ws, kw, cp, sp);
  attn_fwd<<<dim3(2048), blk, 0, stream>>>(q_ws, k_ws, vt_ws, a_ws, qw, cp, sp);
  o_gemm8<<<dim3(512), blk, 0, stream>>>(a_ws, Wo_b, out);
}

// Round 13
// 295.928 us; speedup vs baseline: 1.0105x; 1.0016x over previous
//
#include <hip/hip_runtime.h>
#include <hip/hip_bf16.h>
#include <stdint.h>

typedef __bf16 bf16;
typedef __bf16 bf16x4 __attribute__((ext_vector_type(4)));
typedef __bf16 bf16x8 __attribute__((ext_vector_type(8)));
typedef float floatx4 __attribute__((ext_vector_type(4)));
typedef float floatx8 __attribute__((ext_vector_type(8)));

#define MFMA16(A, B, C) __builtin_amdgcn_mfma_f32_16x16x32_bf16(A, B, C, 0, 0, 0)

constexpr int Sc = 2048, HIDc = 2048, NHc = 32, NKVc = 8, HDc = 64;
constexpr float kScale = 0.125f;          // HD^-0.5
constexpr float kLog2e = 1.44269504089f;
constexpr float kScale2 = kScale * kLog2e; // folded: S' = S*log2e via Q pre-scale
constexpr float kMax2 = 9.0f * kLog2e;     // static max in log2 units

// async 16B global -> LDS (wave-uniform base + lane*16 on the LDS side)
__device__ __forceinline__ void async16(const bf16* g, bf16* l) {
  __builtin_amdgcn_global_load_lds(
      (const __attribute__((address_space(1))) void*)g,
      (__attribute__((address_space(3))) void*)l, 16, 0, 0);
}

// ---------------------------------------------------------------------------
// f32 -> bf16 conversion for hs + 4 weight matrices (blockIdx.y selects).
// ---------------------------------------------------------------------------
__global__ __launch_bounds__(256)
void cvt5(const float* __restrict__ s0, bf16* __restrict__ d0, int n0,
          const float* __restrict__ s1, bf16* __restrict__ d1, int n1,
          const float* __restrict__ s2, bf16* __restrict__ d2, int n2,
          const float* __restrict__ s3, bf16* __restrict__ d3, int n3,
          const float* __restrict__ s4, bf16* __restrict__ d4, int n4)
{
  const float* s; bf16* d; int n;
  switch (blockIdx.y) {
    case 0: s = s0; d = d0; n = n0; break;
    case 1: s = s1; d = d1; n = n1; break;
    case 2: s = s2; d = d2; n = n2; break;
    case 3: s = s3; d = d3; n = n3; break;
    default: s = s4; d = d4; n = n4; break;
  }
  const size_t stride = (size_t)gridDim.x * blockDim.x * 8;
  for (size_t i = ((size_t)blockIdx.x * blockDim.x + threadIdx.x) * 8;
       i < (size_t)n; i += stride) {
    floatx8 f = *(const floatx8*)(s + i);
    bf16x8 o;
#pragma unroll
    for (int j = 0; j < 8; ++j) o[j] = (bf16)f[j];
    *(bf16x8*)(d + i) = o;
  }
}

// ---------------------------------------------------------------------------
// 128x128 pipelined GEMM core, 256 threads / 4 waves (2x2, 64x64 per wave).
// (unchanged from round 10/12 -- verified, tail-race-fixed)
// ---------------------------------------------------------------------------
__device__ __forceinline__
void gemm128_core(const bf16* __restrict__ A, const bf16* __restrict__ Bw,
                  int K, int m0, int n0, bf16* __restrict__ lds,
                  floatx4 (&acc)[4][4])
{
  constexpr int IH = 128 * 32;      // elements per K-half image (8 KB)

  const int tid  = threadIdx.x;     // 0..255
  const int lane = tid & 63;
  const int w    = tid >> 6;        // 0..3
  const int r    = lane & 15;
  const int quad = lane >> 4;
  const int wm   = w >> 1;          // 2 wave rows
  const int wn   = w & 1;           // 2 wave cols
  const int NT   = K >> 6;

  // staging sources, pre-swizzled: chunk ch=(i*256+tid) -> lrow=ch>>3 (0..63),
  // global slot sl=(ch&7)^(lrow&7); sl>>2 = M-half, sl&3 = 16B K-granule.
  const bf16* gA[2]; const bf16* gB[2];
#pragma unroll
  for (int i = 0; i < 2; ++i) {
    const int ch = i * 256 + tid;
    const int lrow = ch >> 3, sl = (ch & 7) ^ (lrow & 7);
    gA[i] = A  + (size_t)(m0 + (sl >> 2) * 64 + lrow) * K + (sl & 3) * 8;
    gB[i] = Bw + (size_t)(n0 + (sl >> 2) * 64 + lrow) * K + (sl & 3) * 8;
  }

  auto stA = [&](int kt, int s, int kk) {
    bf16* dst = lds + (s * 2 + kk) * IH + tid * 8;
#pragma unroll
    for (int i = 0; i < 2; ++i)
      async16(gA[i] + kt * 64 + kk * 32, dst + i * 2048);
  };
  auto stB = [&](int kt, int s, int kk) {
    bf16* dst = lds + 4 * IH + (s * 2 + kk) * IH + tid * 8;
#pragma unroll
    for (int i = 0; i < 2; ++i)
      async16(gB[i] + kt * 64 + kk * 32, dst + i * 2048);
  };

  // read offsets: frag (mt): lrow = mt*16 + r, slot = ((half<<2)+quad)^(r&7)
  const int aoff = r * 64 + (((wm << 2) + quad) ^ (r & 7)) * 8;
  const int boff = r * 64 + (((wn << 2) + quad) ^ (r & 7)) * 8;

  bf16x8 a[4], b[4];

#define LDA(S, KK) do { const bf16* _p = lds + ((S) * 2 + (KK)) * IH + aoff; \
  _Pragma("unroll") for (int m2 = 0; m2 < 4; ++m2) a[m2] = *(const bf16x8*)(_p + m2 * 1024); } while (0)
#define LDB(S, KK) do { const bf16* _p = lds + 4 * IH + ((S) * 2 + (KK)) * IH + boff; \
  _Pragma("unroll") for (int n2 = 0; n2 < 4; ++n2) b[n2] = *(const bf16x8*)(_p + n2 * 1024); } while (0)
#define MM() do { __builtin_amdgcn_s_setprio(1); \
  _Pragma("unroll") for (int m2 = 0; m2 < 4; ++m2) \
    _Pragma("unroll") for (int n2 = 0; n2 < 4; ++n2) \
      acc[m2][n2] = MFMA16(a[m2], b[n2], acc[m2][n2]); \
  __builtin_amdgcn_s_setprio(0); } while (0)
#define BAR() asm volatile("s_barrier" ::: "memory")

  // prologue: tile0 complete + tile1's kk0; certify tile0 (vmcnt(4) leaves
  // exactly the 4 t1-kk0 loads in flight)
  stA(0, 0, 0); stB(0, 0, 0); stA(0, 0, 1); stB(0, 0, 1);
  stA(1, 1, 0); stB(1, 1, 0);
  asm volatile("s_waitcnt vmcnt(4)" ::: "memory"); BAR();

  for (int t = 0; t < NT; ++t) {
    const int s = t & 1;
    // Phase A (kk0) + stage next tile's kk1
    LDA(s, 0); LDB(s, 0);
    if (t + 1 < NT) { stA(t + 1, s ^ 1, 1); stB(t + 1, s ^ 1, 1); }
    BAR(); MM(); BAR();
    // Phase B (kk1) + stage tile t+2's kk0
    LDA(s, 1); LDB(s, 1);
    if (t + 2 < NT) { stA(t + 2, s, 0); stB(t + 2, s, 0); }
    BAR(); MM();
    // gate: certify tile t+1's four halves. Counted only while S_B(t) was
    // issued; otherwise FULL drain (tail-race fix, verified r10).
    if (t + 2 < NT) asm volatile("s_waitcnt vmcnt(4)" ::: "memory");
    else            asm volatile("s_waitcnt vmcnt(0)" ::: "memory");
    BAR();
  }

#undef LDA
#undef LDB
#undef MM
#undef BAR
}

// ---- epilogues (wave tile 64x64: row base wm*64, col base wn*64) -----------
template<bool CF32>
__device__ __forceinline__
void epi_plain(const floatx4 (&acc)[4][4], void* C, int N, int m0, int n0,
               int wm, int wn, int r, int quad)
{
#pragma unroll
  for (int mt = 0; mt < 4; ++mt) {
#pragma unroll
    for (int nt = 0; nt < 4; ++nt) {
      const int row = m0 + wm * 64 + mt * 16 + quad * 4;
      const int col = n0 + wn * 64 + nt * 16 + r;
#pragma unroll
      for (int g = 0; g < 4; ++g) {
        const size_t ci = (size_t)(row + g) * N + col;
        if constexpr (CF32) ((float*)C)[ci] = acc[mt][nt][g];
        else                ((bf16*)C)[ci]  = (bf16)acc[mt][nt][g];
      }
    }
  }
}

// K path: fused RMSNorm (f32 acc) + RoPE, store bf16 to k_ws [token][h*64+d].
__device__ __forceinline__
void epi_k(const floatx4 (&acc)[4][4], bf16* kws, const float* kw,
           const float* cp, const float* sp, int m0, int n0,
           int wm, int wn, int r, int quad)
{
  const int h = (n0 >> 6) + wn;                    // 0..7
  const float w0 = kw[r], w1 = kw[16 + r], w2 = kw[32 + r], w3 = kw[48 + r];
#pragma unroll
  for (int mt = 0; mt < 4; ++mt) {
#pragma unroll
    for (int g = 0; g < 4; ++g) {
      const int row = m0 + wm * 64 + mt * 16 + quad * 4 + g;
      const float x0 = acc[mt][0][g], x1 = acc[mt][1][g];
      const float x2 = acc[mt][2][g], x3 = acc[mt][3][g];
      float ss = x0 * x0 + x1 * x1 + x2 * x2 + x3 * x3;
      ss += __shfl_xor(ss, 1); ss += __shfl_xor(ss, 2);
      ss += __shfl_xor(ss, 4); ss += __shfl_xor(ss, 8);
      const float rr = rsqrtf(ss * (1.0f / 64.0f) + 1e-6f);
      const float y0 = x0 * rr * w0, y1 = x1 * rr * w1;
      const float y2 = x2 * rr * w2, y3 = x3 * rr * w3;
      const float* cb = cp + (size_t)row * 64 + r;
      const float* sb = sp + (size_t)row * 64 + r;
      bf16* p = kws + (size_t)row * 512 + h * 64 + r;
      p[0]  = (bf16)(y0 * cb[0]  - y2 * sb[0]);
      p[16] = (bf16)(y1 * cb[16] - y3 * sb[16]);
      p[32] = (bf16)(y2 * cb[32] + y0 * sb[32]);
      p[48] = (bf16)(y3 * cb[48] + y1 * sb[48]);
    }
  }
}

// V path: store transposed directly into vt [((b*8+kvh)*64+d)*2048 + s].
__device__ __forceinline__
void epi_v(const floatx4 (&acc)[4][4], bf16* vt, int m0, int n0,
           int wm, int wn, int r, int quad)
{
  const int kvh = (n0 >> 6) + wn;                  // 0..7
  const int b   = m0 >> 11;
  const int sb  = (m0 & 2047) + wm * 64 + quad * 4;
#pragma unroll
  for (int mt = 0; mt < 4; ++mt) {
#pragma unroll
    for (int nt = 0; nt < 4; ++nt) {
      const int d = nt * 16 + r;
      bf16x4 pk;
#pragma unroll
      for (int g = 0; g < 4; ++g) pk[g] = (bf16)acc[mt][nt][g];
      *(bf16x4*)(vt + ((size_t)((b * 8 + kvh) * 64 + d)) * Sc + sb + mt * 16) = pk;
    }
  }
}

__global__ __launch_bounds__(256, 2)
void qkv_gemm8(const bf16* __restrict__ hs,
               const bf16* __restrict__ Wq, const bf16* __restrict__ Wk,
               const bf16* __restrict__ Wv,
               bf16* __restrict__ q_ws, bf16* __restrict__ k_ws,
               bf16* __restrict__ vt_ws,
               const float* __restrict__ kw, const float* __restrict__ cp,
               const float* __restrict__ sp)
{
  __shared__ bf16 lds[8 * 128 * 32];               // 64 KiB -> 2 blocks/CU
  const int wg  = blockIdx.x;
  const int swz = (wg & 7) * 96 + (wg >> 3);       // 768 blocks, bijective
  const int mi  = swz / 24, ni = swz % 24;
  const bf16* Bw; int n0;
  if (ni < 16)      { Bw = Wq; n0 = ni * 128; }
  else if (ni < 20) { Bw = Wk; n0 = (ni - 16) * 128; }
  else              { Bw = Wv; n0 = (ni - 20) * 128; }

  floatx4 acc[4][4] = {};
  gemm128_core(hs, Bw, HIDc, mi * 128, n0, lds, acc);

  const int lane = threadIdx.x & 63, w = threadIdx.x >> 6;
  const int r = lane & 15, quad = lane >> 4;
  const int wm = w >> 1, wn = w & 1;
  if (ni < 16)
    epi_plain<false>(acc, q_ws, 2048, mi * 128, n0, wm, wn, r, quad);
  else if (ni < 20)
    epi_k(acc, k_ws, kw, cp, sp, mi * 128, n0, wm, wn, r, quad);
  else
    epi_v(acc, vt_ws, mi * 128, n0, wm, wn, r, quad);
}

__global__ __launch_bounds__(256, 2)
void o_gemm8(const bf16* __restrict__ a_ws, const bf16* __restrict__ Wo,
             float* __restrict__ out)
{
  __shared__ bf16 lds[8 * 128 * 32];               // 64 KiB -> 2 blocks/CU
  const int wg  = blockIdx.x;
  const int swz = (wg & 7) * 64 + (wg >> 3);       // 512 blocks, bijective
  const int mi  = swz >> 4, ni = swz & 15;

  floatx4 acc[4][4] = {};
  gemm128_core(a_ws, Wo, NHc * HDc, mi * 128, ni * 128, lds, acc);

  const int lane = threadIdx.x & 63, w = threadIdx.x >> 6;
  const int r = lane & 15, quad = lane >> 4;
  const int wm = w >> 1, wn = w & 1;
  epi_plain<true>(acc, out, HIDc, mi * 128, ni * 128, wm, wn, r, quad);
}

// ---------------------------------------------------------------------------
// Causal flash attention, GQA groups=4, fused Q RMSNorm+RoPE, static-max
// softmax in LOG2 units (log2e folded into Q pre-scale -> p = exp2(sa-kMax2),
// no per-element v_mul; r12's counters: VALUBusy 40% was top pipe).
// SWAPPED QK^T (mfma(K,Q) -- same LDS fragments, operand order only):
// output is S^T, so thread (r,quad) holds P[q=r][kv=16nt+4quad+g] -- the 4
// g-values are kv-contiguous -> Ps writes become 4x ds_write_b64 (was 16
// scalar ds_write_b16, the bank-conflict suspect). Ps READ layout/addresses
// unchanged (row-major [q][72], pa0/pa1 b128). lsum is now a per-thread
// scalar (all 16 values share q=r); epilogue reduces over lanes {r,r+16,
// r+32,r+48} (2 shfls) and redistributes via shfl(l, quad*4+reg).
// ONE q-tile per block (2048 blocks, heavy-first), launch_bounds(256,6),
// single-buffer staging with the 5x-verified {sync; stage; sync; compute}.
// o aliases q (block-exclusive regions).
// ---------------------------------------------------------------------------
__global__ __launch_bounds__(256, 6)
void attn_fwd(const bf16* __restrict__ q, const bf16* __restrict__ k,
              const bf16* __restrict__ vt, bf16* __restrict__ o,
              const float* __restrict__ qw, const float* __restrict__ cp,
              const float* __restrict__ sp)
{
  __shared__ bf16 Ks[64 * 64];
  __shared__ bf16 Vs[64 * 64];        // V^T [d][kv], swizzled
  __shared__ bf16 Ps[4][16 * 72];     // per-wave P round-trip, stride 72

  const int bi  = blockIdx.x;          // 0..2047
  const int qt  = 31 - (bi >> 6);      // heavy q-tiles first in dispatch order
  const int hb  = bi & 63;
  const int h   = hb & 31;
  const int b   = hb >> 5;
  const int kvh = h >> 2;
  const int tid = threadIdx.x, lane = tid & 63, w = tid >> 6;
  const int r = lane & 15, quad = lane >> 4;

  // Q load + fused RMSNorm (kScale2 = scale*log2e folded in) + RoPE
  const floatx8 w0 = *(const floatx8*)(qw + quad * 8);
  const floatx8 w1 = *(const floatx8*)(qw + 32 + quad * 8);
  bf16x8 qf0, qf1;
  {
    const int m = b * Sc + qt * 64 + w * 16 + r;
    const bf16* qp = q + (size_t)m * (NHc * HDc) + h * HDc + quad * 8;
    bf16x8 x0 = *(const bf16x8*)qp;
    bf16x8 x1 = *(const bf16x8*)(qp + 32);
    float ss = 0.f;
#pragma unroll
    for (int i = 0; i < 8; ++i)
      ss += (float)x0[i] * (float)x0[i] + (float)x1[i] * (float)x1[i];
    ss += __shfl_xor(ss, 16);
    ss += __shfl_xor(ss, 32);
    const float rq = rsqrtf(ss * (1.0f / 64.0f) + 1e-6f) * kScale2;
    const floatx8 c0 = *(const floatx8*)(cp + (size_t)m * 64 + quad * 8);
    const floatx8 c1 = *(const floatx8*)(cp + (size_t)m * 64 + 32 + quad * 8);
    const floatx8 s0 = *(const floatx8*)(sp + (size_t)m * 64 + quad * 8);
    const floatx8 s1 = *(const floatx8*)(sp + (size_t)m * 64 + 32 + quad * 8);
#pragma unroll
    for (int i = 0; i < 8; ++i) {
      const float y0 = (float)x0[i] * rq * w0[i];
      const float y1 = (float)x1[i] * rq * w1[i];
      qf0[i] = (bf16)(y0 * c0[i] - y1 * s0[i]);   // d < 32
      qf1[i] = (bf16)(y1 * c1[i] + y0 * s1[i]);   // d >= 32
    }
  }

  floatx4 accO[4] = {};
  float lsum = 0.f;                    // scalar: all 16 P values share q=r

  const int kvr = tid >> 3;            // staging row (0..31), +32 for seg1
  const int cx  = ((tid & 7) * 8) ^ (8 * (kvr & 7));  // swizzle on GLOBAL side
  const int xk  = 8 * (r & 7);                        // read-side XOR

  const bf16* kp = k + (size_t)b * Sc * (NKVc * HDc) + kvh * HDc;
  const bf16* vp = vt + ((size_t)((b * NKVc + kvh) * 64)) * Sc;

  for (int j = 0; j <= qt; ++j) {
    __syncthreads();                 // prior tile's fragment reads done (WAR)
    {
      const bf16* kj = kp + (size_t)j * 64 * (NKVc * HDc);
      const bf16* vj = vp + j * 64;
      async16(kj + (size_t)kvr * (NKVc * HDc) + cx, Ks + tid * 8);
      async16(kj + (size_t)(kvr + 32) * (NKVc * HDc) + cx, Ks + (tid + 256) * 8);
      async16(vj + (size_t)kvr * Sc + cx, Vs + tid * 8);
      async16(vj + (size_t)(kvr + 32) * Sc + cx, Vs + (tid + 256) * 8);
    }
    __syncthreads();                 // drain async loads

    // S^T = K Q^T (64 x 16 per wave), pre-scaled in log2 units.
    // Thread (r,quad) reg g of sa[nt] = S[q=r][kv=16nt+4quad+g].
    floatx4 sa[4];
#pragma unroll
    for (int nt = 0; nt < 4; ++nt) sa[nt] = floatx4{0.f, 0.f, 0.f, 0.f};
    __builtin_amdgcn_s_setprio(1);
#pragma unroll
    for (int nt = 0; nt < 4; ++nt) {
      const int kv = nt * 16 + r;
      const bf16x8 kb0 = *(const bf16x8*)(&Ks[kv * 64 + ((quad * 8) ^ xk)]);
      const bf16x8 kb1 = *(const bf16x8*)(&Ks[kv * 64 + ((quad * 8 + 32) ^ xk)]);
      sa[nt] = MFMA16(kb0, qf0, sa[nt]);   // swapped operands -> S^T
      sa[nt] = MFMA16(kb1, qf1, sa[nt]);
    }
    __builtin_amdgcn_s_setprio(0);

    // static-max softmax (exp2); packed b64 Ps writes; mask only on diag
    if (j != qt) {
#pragma unroll
      for (int nt = 0; nt < 4; ++nt) {
        bf16x4 pk;
#pragma unroll
        for (int g = 0; g < 4; ++g) {
          const float p = exp2f(sa[nt][g] - kMax2);
          lsum += p;
          pk[g] = (bf16)p;
        }
        *(bf16x4*)(&Ps[w][r * 72 + nt * 16 + quad * 4]) = pk;
      }
    } else {
      const int qloc = w * 16 + r;
#pragma unroll
      for (int nt = 0; nt < 4; ++nt) {
        bf16x4 pk;
#pragma unroll
        for (int g = 0; g < 4; ++g) {
          const float p = (nt * 16 + quad * 4 + g <= qloc)
                              ? exp2f(sa[nt][g] - kMax2) : 0.f;
          lsum += p;
          pk[g] = (bf16)p;
        }
        *(bf16x4*)(&Ps[w][r * 72 + nt * 16 + quad * 4]) = pk;
      }
    }

    const bf16x8 pa0 = *(const bf16x8*)(&Ps[w][r * 72 + quad * 8]);
    const bf16x8 pa1 = *(const bf16x8*)(&Ps[w][r * 72 + 32 + quad * 8]);
    __builtin_amdgcn_s_setprio(1);
#pragma unroll
    for (int dt = 0; dt < 4; ++dt) {
      const int d = dt * 16 + r;
      const bf16x8 vb0 = *(const bf16x8*)(&Vs[d * 64 + ((quad * 8) ^ xk)]);
      const bf16x8 vb1 = *(const bf16x8*)(&Vs[d * 64 + ((quad * 8 + 32) ^ xk)]);
      accO[dt] = MFMA16(pa0, vb0, accO[dt]);
      accO[dt] = MFMA16(pa1, vb1, accO[dt]);
    }
    __builtin_amdgcn_s_setprio(0);
  }

  // epilogue: l lives per q=r on lanes {r,r+16,r+32,r+48}; reduce, then
  // redistribute to the accO layout (row q16 = quad*4+reg).
  float l = lsum;
  l += __shfl_xor(l, 16);
  l += __shfl_xor(l, 32);
#pragma unroll
  for (int reg = 0; reg < 4; ++reg) {
    const float inv = 1.0f / __shfl(l, quad * 4 + reg);
    const size_t row = (size_t)(b * Sc + qt * 64 + w * 16 + quad * 4 + reg);
#pragma unroll
    for (int dt = 0; dt < 4; ++dt)
      o[row * (NHc * HDc) + h * HDc + dt * 16 + r] = (bf16)(accO[dt][reg] * inv);
  }
}

// ---------------------------------------------------------------------------
extern "C" void kernel_launch(void* const* d_in, const int* in_sizes, int n_in,
                              void* d_out, int out_size, void* d_ws, size_t ws_size,
                              hipStream_t stream)
{
  const float* hs = (const float*)d_in[0];
  const float* cp = (const float*)d_in[1];
  const float* sp = (const float*)d_in[2];
  const float* Wq = (const float*)d_in[3];
  const float* Wk = (const float*)d_in[4];
  const float* Wv = (const float*)d_in[5];
  const float* Wo = (const float*)d_in[6];
  const float* qw = (const float*)d_in[7];
  const float* kw = (const float*)d_in[8];
  float* out = (float*)d_out;

  char* ws = (char*)d_ws;
  bf16* q_ws  = (bf16*)ws;                      // 16 MiB
  bf16* k_ws  = (bf16*)(ws + (16u << 20));      // 4 MiB
  bf16* vt_ws = (bf16*)(ws + (24u << 20));      // 4 MiB
  bf16* hs_b  = (bf16*)(ws + (28u << 20));      // 16 MiB
  bf16* Wq_b  = (bf16*)(ws + (44u << 20));      // 8 MiB
  bf16* Wk_b  = (bf16*)(ws + (52u << 20));      // 2 MiB
  bf16* Wv_b  = (bf16*)(ws + (54u << 20));      // 2 MiB
  bf16* Wo_b  = (bf16*)(ws + (56u << 20));      // 8 MiB -> 64 MiB total
  bf16* a_ws  = q_ws;                           // safe alias (see attn_fwd)

  dim3 blk(256);
  cvt5<<<dim3(256, 5), blk, 0, stream>>>(
      hs, hs_b, 4096 * 2048, Wq, Wq_b, 2048 * 2048, Wk, Wk_b, 512 * 2048,
      Wv, Wv_b, 512 * 2048, Wo, Wo_b, 2048 * 2048);
  qkv_gemm8<<<dim3(768), blk, 0, stream>>>(hs_b, Wq_b, Wk_b, Wv_b,
                                           q_ws, k_ws, vt_ws, kw, cp, sp);
  attn_fwd<<<dim3(2048), blk, 0, stream>>>(q_ws, k_ws, vt_ws, a_ws, qw, cp, sp);
  o_gemm8<<<dim3(512), blk, 0, stream>>>(a_ws, Wo_b, out);
}

// Round 14
// 295.062 us; speedup vs baseline: 1.0135x; 1.0029x over previous
//
#include <hip/hip_runtime.h>
#include <hip/hip_bf16.h>
#include <stdint.h>

typedef __bf16 bf16;
typedef __bf16 bf16x4 __attribute__((ext_vector_type(4)));
typedef __bf16 bf16x8 __attribute__((ext_vector_type(8)));
typedef float floatx4 __attribute__((ext_vector_type(4)));
typedef float floatx8 __attribute__((ext_vector_type(8)));

#define MFMA16(A, B, C) __builtin_amdgcn_mfma_f32_16x16x32_bf16(A, B, C, 0, 0, 0)

constexpr int Sc = 2048, HIDc = 2048, NHc = 32, NKVc = 8, HDc = 64;
constexpr float kScale = 0.125f;          // HD^-0.5
constexpr float kLog2e = 1.44269504089f;
constexpr float kScale2 = kScale * kLog2e; // folded: S' = S*log2e via Q pre-scale
constexpr float kMax2 = 9.0f * kLog2e;     // static max in log2 units
constexpr int PSTR = 88;                   // Ps stride: bank-spread for b64 writes

// async 16B global -> LDS (wave-uniform base + lane*16 on the LDS side)
__device__ __forceinline__ void async16(const bf16* g, bf16* l) {
  __builtin_amdgcn_global_load_lds(
      (const __attribute__((address_space(1))) void*)g,
      (__attribute__((address_space(3))) void*)l, 16, 0, 0);
}

// ---------------------------------------------------------------------------
// f32 -> bf16 conversion for hs + 4 weight matrices (blockIdx.y selects).
// ---------------------------------------------------------------------------
__global__ __launch_bounds__(256)
void cvt5(const float* __restrict__ s0, bf16* __restrict__ d0, int n0,
          const float* __restrict__ s1, bf16* __restrict__ d1, int n1,
          const float* __restrict__ s2, bf16* __restrict__ d2, int n2,
          const float* __restrict__ s3, bf16* __restrict__ d3, int n3,
          const float* __restrict__ s4, bf16* __restrict__ d4, int n4)
{
  const float* s; bf16* d; int n;
  switch (blockIdx.y) {
    case 0: s = s0; d = d0; n = n0; break;
    case 1: s = s1; d = d1; n = n1; break;
    case 2: s = s2; d = d2; n = n2; break;
    case 3: s = s3; d = d3; n = n3; break;
    default: s = s4; d = d4; n = n4; break;
  }
  const size_t stride = (size_t)gridDim.x * blockDim.x * 8;
  for (size_t i = ((size_t)blockIdx.x * blockDim.x + threadIdx.x) * 8;
       i < (size_t)n; i += stride) {
    floatx8 f = *(const floatx8*)(s + i);
    bf16x8 o;
#pragma unroll
    for (int j = 0; j < 8; ++j) o[j] = (bf16)f[j];
    *(bf16x8*)(d + i) = o;
  }
}

// ---------------------------------------------------------------------------
// 128x128 pipelined GEMM core, 256 threads / 4 waves (2x2, 64x64 per wave).
// (unchanged from round 10/13 -- verified, tail-race-fixed)
// ---------------------------------------------------------------------------
__device__ __forceinline__
void gemm128_core(const bf16* __restrict__ A, const bf16* __restrict__ Bw,
                  int K, int m0, int n0, bf16* __restrict__ lds,
                  floatx4 (&acc)[4][4])
{
  constexpr int IH = 128 * 32;      // elements per K-half image (8 KB)

  const int tid  = threadIdx.x;     // 0..255
  const int lane = tid & 63;
  const int w    = tid >> 6;        // 0..3
  const int r    = lane & 15;
  const int quad = lane >> 4;
  const int wm   = w >> 1;          // 2 wave rows
  const int wn   = w & 1;           // 2 wave cols
  const int NT   = K >> 6;

  // staging sources, pre-swizzled: chunk ch=(i*256+tid) -> lrow=ch>>3 (0..63),
  // global slot sl=(ch&7)^(lrow&7); sl>>2 = M-half, sl&3 = 16B K-granule.
  const bf16* gA[2]; const bf16* gB[2];
#pragma unroll
  for (int i = 0; i < 2; ++i) {
    const int ch = i * 256 + tid;
    const int lrow = ch >> 3, sl = (ch & 7) ^ (lrow & 7);
    gA[i] = A  + (size_t)(m0 + (sl >> 2) * 64 + lrow) * K + (sl & 3) * 8;
    gB[i] = Bw + (size_t)(n0 + (sl >> 2) * 64 + lrow) * K + (sl & 3) * 8;
  }

  auto stA = [&](int kt, int s, int kk) {
    bf16* dst = lds + (s * 2 + kk) * IH + tid * 8;
#pragma unroll
    for (int i = 0; i < 2; ++i)
      async16(gA[i] + kt * 64 + kk * 32, dst + i * 2048);
  };
  auto stB = [&](int kt, int s, int kk) {
    bf16* dst = lds + 4 * IH + (s * 2 + kk) * IH + tid * 8;
#pragma unroll
    for (int i = 0; i < 2; ++i)
      async16(gB[i] + kt * 64 + kk * 32, dst + i * 2048);
  };

  // read offsets: frag (mt): lrow = mt*16 + r, slot = ((half<<2)+quad)^(r&7)
  const int aoff = r * 64 + (((wm << 2) + quad) ^ (r & 7)) * 8;
  const int boff = r * 64 + (((wn << 2) + quad) ^ (r & 7)) * 8;

  bf16x8 a[4], b[4];

#define LDA(S, KK) do { const bf16* _p = lds + ((S) * 2 + (KK)) * IH + aoff; \
  _Pragma("unroll") for (int m2 = 0; m2 < 4; ++m2) a[m2] = *(const bf16x8*)(_p + m2 * 1024); } while (0)
#define LDB(S, KK) do { const bf16* _p = lds + 4 * IH + ((S) * 2 + (KK)) * IH + boff; \
  _Pragma("unroll") for (int n2 = 0; n2 < 4; ++n2) b[n2] = *(const bf16x8*)(_p + n2 * 1024); } while (0)
#define MM() do { __builtin_amdgcn_s_setprio(1); \
  _Pragma("unroll") for (int m2 = 0; m2 < 4; ++m2) \
    _Pragma("unroll") for (int n2 = 0; n2 < 4; ++n2) \
      acc[m2][n2] = MFMA16(a[m2], b[n2], acc[m2][n2]); \
  __builtin_amdgcn_s_setprio(0); } while (0)
#define BAR() asm volatile("s_barrier" ::: "memory")

  // prologue: tile0 complete + tile1's kk0; certify tile0 (vmcnt(4) leaves
  // exactly the 4 t1-kk0 loads in flight)
  stA(0, 0, 0); stB(0, 0, 0); stA(0, 0, 1); stB(0, 0, 1);
  stA(1, 1, 0); stB(1, 1, 0);
  asm volatile("s_waitcnt vmcnt(4)" ::: "memory"); BAR();

  for (int t = 0; t < NT; ++t) {
    const int s = t & 1;
    // Phase A (kk0) + stage next tile's kk1
    LDA(s, 0); LDB(s, 0);
    if (t + 1 < NT) { stA(t + 1, s ^ 1, 1); stB(t + 1, s ^ 1, 1); }
    BAR(); MM(); BAR();
    // Phase B (kk1) + stage tile t+2's kk0
    LDA(s, 1); LDB(s, 1);
    if (t + 2 < NT) { stA(t + 2, s, 0); stB(t + 2, s, 0); }
    BAR(); MM();
    // gate: certify tile t+1's four halves. Counted only while S_B(t) was
    // issued; otherwise FULL drain (tail-race fix, verified r10).
    if (t + 2 < NT) asm volatile("s_waitcnt vmcnt(4)" ::: "memory");
    else            asm volatile("s_waitcnt vmcnt(0)" ::: "memory");
    BAR();
  }

#undef LDA
#undef LDB
#undef MM
#undef BAR
}

// ---- epilogues (wave tile 64x64: row base wm*64, col base wn*64) -----------
template<bool CF32>
__device__ __forceinline__
void epi_plain(const floatx4 (&acc)[4][4], void* C, int N, int m0, int n0,
               int wm, int wn, int r, int quad)
{
#pragma unroll
  for (int mt = 0; mt < 4; ++mt) {
#pragma unroll
    for (int nt = 0; nt < 4; ++nt) {
      const int row = m0 + wm * 64 + mt * 16 + quad * 4;
      const int col = n0 + wn * 64 + nt * 16 + r;
#pragma unroll
      for (int g = 0; g < 4; ++g) {
        const size_t ci = (size_t)(row + g) * N + col;
        if constexpr (CF32) ((float*)C)[ci] = acc[mt][nt][g];
        else                ((bf16*)C)[ci]  = (bf16)acc[mt][nt][g];
      }
    }
  }
}

// K path: fused RMSNorm (f32 acc) + RoPE, store bf16 to k_ws [token][h*64+d].
__device__ __forceinline__
void epi_k(const floatx4 (&acc)[4][4], bf16* kws, const float* kw,
           const float* cp, const float* sp, int m0, int n0,
           int wm, int wn, int r, int quad)
{
  const int h = (n0 >> 6) + wn;                    // 0..7
  const float w0 = kw[r], w1 = kw[16 + r], w2 = kw[32 + r], w3 = kw[48 + r];
#pragma unroll
  for (int mt = 0; mt < 4; ++mt) {
#pragma unroll
    for (int g = 0; g < 4; ++g) {
      const int row = m0 + wm * 64 + mt * 16 + quad * 4 + g;
      const float x0 = acc[mt][0][g], x1 = acc[mt][1][g];
      const float x2 = acc[mt][2][g], x3 = acc[mt][3][g];
      float ss = x0 * x0 + x1 * x1 + x2 * x2 + x3 * x3;
      ss += __shfl_xor(ss, 1); ss += __shfl_xor(ss, 2);
      ss += __shfl_xor(ss, 4); ss += __shfl_xor(ss, 8);
      const float rr = rsqrtf(ss * (1.0f / 64.0f) + 1e-6f);
      const float y0 = x0 * rr * w0, y1 = x1 * rr * w1;
      const float y2 = x2 * rr * w2, y3 = x3 * rr * w3;
      const float* cb = cp + (size_t)row * 64 + r;
      const float* sb = sp + (size_t)row * 64 + r;
      bf16* p = kws + (size_t)row * 512 + h * 64 + r;
      p[0]  = (bf16)(y0 * cb[0]  - y2 * sb[0]);
      p[16] = (bf16)(y1 * cb[16] - y3 * sb[16]);
      p[32] = (bf16)(y2 * cb[32] + y0 * sb[32]);
      p[48] = (bf16)(y3 * cb[48] + y1 * sb[48]);
    }
  }
}

// V path: store transposed directly into vt [((b*8+kvh)*64+d)*2048 + s].
__device__ __forceinline__
void epi_v(const floatx4 (&acc)[4][4], bf16* vt, int m0, int n0,
           int wm, int wn, int r, int quad)
{
  const int kvh = (n0 >> 6) + wn;                  // 0..7
  const int b   = m0 >> 11;
  const int sb  = (m0 & 2047) + wm * 64 + quad * 4;
#pragma unroll
  for (int mt = 0; mt < 4; ++mt) {
#pragma unroll
    for (int nt = 0; nt < 4; ++nt) {
      const int d = nt * 16 + r;
      bf16x4 pk;
#pragma unroll
      for (int g = 0; g < 4; ++g) pk[g] = (bf16)acc[mt][nt][g];
      *(bf16x4*)(vt + ((size_t)((b * 8 + kvh) * 64 + d)) * Sc + sb + mt * 16) = pk;
    }
  }
}

__global__ __launch_bounds__(256, 2)
void qkv_gemm8(const bf16* __restrict__ hs,
               const bf16* __restrict__ Wq, const bf16* __restrict__ Wk,
               const bf16* __restrict__ Wv,
               bf16* __restrict__ q_ws, bf16* __restrict__ k_ws,
               bf16* __restrict__ vt_ws,
               const float* __restrict__ kw, const float* __restrict__ cp,
               const float* __restrict__ sp)
{
  __shared__ bf16 lds[8 * 128 * 32];               // 64 KiB -> 2 blocks/CU
  const int wg  = blockIdx.x;
  const int swz = (wg & 7) * 96 + (wg >> 3);       // 768 blocks, bijective
  const int mi  = swz / 24, ni = swz % 24;
  const bf16* Bw; int n0;
  if (ni < 16)      { Bw = Wq; n0 = ni * 128; }
  else if (ni < 20) { Bw = Wk; n0 = (ni - 16) * 128; }
  else              { Bw = Wv; n0 = (ni - 20) * 128; }

  floatx4 acc[4][4] = {};
  gemm128_core(hs, Bw, HIDc, mi * 128, n0, lds, acc);

  const int lane = threadIdx.x & 63, w = threadIdx.x >> 6;
  const int r = lane & 15, quad = lane >> 4;
  const int wm = w >> 1, wn = w & 1;
  if (ni < 16)
    epi_plain<false>(acc, q_ws, 2048, mi * 128, n0, wm, wn, r, quad);
  else if (ni < 20)
    epi_k(acc, k_ws, kw, cp, sp, mi * 128, n0, wm, wn, r, quad);
  else
    epi_v(acc, vt_ws, mi * 128, n0, wm, wn, r, quad);
}

__global__ __launch_bounds__(256, 2)
void o_gemm8(const bf16* __restrict__ a_ws, const bf16* __restrict__ Wo,
             float* __restrict__ out)
{
  __shared__ bf16 lds[8 * 128 * 32];               // 64 KiB -> 2 blocks/CU
  const int wg  = blockIdx.x;
  const int swz = (wg & 7) * 64 + (wg >> 3);       // 512 blocks, bijective
  const int mi  = swz >> 4, ni = swz & 15;

  floatx4 acc[4][4] = {};
  gemm128_core(a_ws, Wo, NHc * HDc, mi * 128, ni * 128, lds, acc);

  const int lane = threadIdx.x & 63, w = threadIdx.x >> 6;
  const int r = lane & 15, quad = lane >> 4;
  const int wm = w >> 1, wn = w & 1;
  epi_plain<true>(acc, out, HIDc, mi * 128, ni * 128, wm, wn, r, quad);
}

// ---------------------------------------------------------------------------
// Causal flash attention, GQA groups=4, fused Q RMSNorm+RoPE, static-max
// softmax in LOG2 units, swapped QK^T (S^T; packed b64 Ps writes) -- r13
// verified math, byte-identical per element.
// r14 changes (both counter-driven):
// 1. PAIR-STAGING: stage K/V for tiles j and j+1 into two independent 8KB
//    buffers in one {sync; stage x2; sync} window, compute both sequentially
//    -> 17 drain events per block instead of 33 (r13: ~23% true idle =
//    vmcnt(0) drains). LDS 43KB -> 3 blocks/CU; r12 showed attn is NOT
//    TLP-limited (occ 33->52 was flat), so the occupancy cost is tolerable.
// 2. Ps stride 72 -> 88: r13's b64 writes at stride 72 alias (bank =
//    r*36+nt*8+quad*2 mod 32; r/r+8 collide) -> conflicts tripled to 3.24M.
//    Stride 88: write banks (r*12+nt*8+quad*2)%32 spread ~4-way; b128 reads
//    ~2-way (free, m136); 16B alignment holds (176r % 16 == 0).
// ONE q-tile per block (2048 blocks, heavy-first). o aliases q.
// ---------------------------------------------------------------------------
__global__ __launch_bounds__(256, 3)
void attn_fwd(const bf16* __restrict__ q, const bf16* __restrict__ k,
              const bf16* __restrict__ vt, bf16* __restrict__ o,
              const float* __restrict__ qw, const float* __restrict__ cp,
              const float* __restrict__ sp)
{
  __shared__ bf16 Ks[2][64 * 64];
  __shared__ bf16 Vs[2][64 * 64];     // V^T [d][kv], swizzled
  __shared__ bf16 Ps[4][16 * PSTR];   // per-wave P round-trip

  const int bi  = blockIdx.x;          // 0..2047
  const int qt  = 31 - (bi >> 6);      // heavy q-tiles first in dispatch order
  const int hb  = bi & 63;
  const int h   = hb & 31;
  const int b   = hb >> 5;
  const int kvh = h >> 2;
  const int tid = threadIdx.x, lane = tid & 63, w = tid >> 6;
  const int r = lane & 15, quad = lane >> 4;

  // Q load + fused RMSNorm (kScale2 = scale*log2e folded in) + RoPE
  const floatx8 w0 = *(const floatx8*)(qw + quad * 8);
  const floatx8 w1 = *(const floatx8*)(qw + 32 + quad * 8);
  bf16x8 qf0, qf1;
  {
    const int m = b * Sc + qt * 64 + w * 16 + r;
    const bf16* qp = q + (size_t)m * (NHc * HDc) + h * HDc + quad * 8;
    bf16x8 x0 = *(const bf16x8*)qp;
    bf16x8 x1 = *(const bf16x8*)(qp + 32);
    float ss = 0.f;
#pragma unroll
    for (int i = 0; i < 8; ++i)
      ss += (float)x0[i] * (float)x0[i] + (float)x1[i] * (float)x1[i];
    ss += __shfl_xor(ss, 16);
    ss += __shfl_xor(ss, 32);
    const float rq = rsqrtf(ss * (1.0f / 64.0f) + 1e-6f) * kScale2;
    const floatx8 c0 = *(const floatx8*)(cp + (size_t)m * 64 + quad * 8);
    const floatx8 c1 = *(const floatx8*)(cp + (size_t)m * 64 + 32 + quad * 8);
    const floatx8 s0 = *(const floatx8*)(sp + (size_t)m * 64 + quad * 8);
    const floatx8 s1 = *(const floatx8*)(sp + (size_t)m * 64 + 32 + quad * 8);
#pragma unroll
    for (int i = 0; i < 8; ++i) {
      const float y0 = (float)x0[i] * rq * w0[i];
      const float y1 = (float)x1[i] * rq * w1[i];
      qf0[i] = (bf16)(y0 * c0[i] - y1 * s0[i]);   // d < 32
      qf1[i] = (bf16)(y1 * c1[i] + y0 * s1[i]);   // d >= 32
    }
  }

  floatx4 accO[4] = {};
  float lsum = 0.f;                    // scalar: all 16 P values share q=r

  const int kvr = tid >> 3;            // staging row (0..31), +32 for seg1
  const int cx  = ((tid & 7) * 8) ^ (8 * (kvr & 7));  // swizzle on GLOBAL side
  const int xk  = 8 * (r & 7);                        // read-side XOR

  const bf16* kp = k + (size_t)b * Sc * (NKVc * HDc) + kvh * HDc;
  const bf16* vp = vt + ((size_t)((b * NKVc + kvh) * 64)) * Sc;

  auto stage = [&](int j, int s) {
    const bf16* kj = kp + (size_t)j * 64 * (NKVc * HDc);
    const bf16* vj = vp + j * 64;
    async16(kj + (size_t)kvr * (NKVc * HDc) + cx, Ks[s] + tid * 8);
    async16(kj + (size_t)(kvr + 32) * (NKVc * HDc) + cx, Ks[s] + (tid + 256) * 8);
    async16(vj + (size_t)kvr * Sc + cx, Vs[s] + tid * 8);
    async16(vj + (size_t)(kvr + 32) * Sc + cx, Vs[s] + (tid + 256) * 8);
  };

  auto comp = [&](int jj, int s) {
    const bf16* Kb = Ks[s];
    const bf16* Vb = Vs[s];
    // S^T = K Q^T: thread (r,quad) reg g of sa[nt] = S[q=r][kv=16nt+4quad+g]
    floatx4 sa[4];
#pragma unroll
    for (int nt = 0; nt < 4; ++nt) sa[nt] = floatx4{0.f, 0.f, 0.f, 0.f};
    __builtin_amdgcn_s_setprio(1);
#pragma unroll
    for (int nt = 0; nt < 4; ++nt) {
      const int kv = nt * 16 + r;
      const bf16x8 kb0 = *(const bf16x8*)(&Kb[kv * 64 + ((quad * 8) ^ xk)]);
      const bf16x8 kb1 = *(const bf16x8*)(&Kb[kv * 64 + ((quad * 8 + 32) ^ xk)]);
      sa[nt] = MFMA16(kb0, qf0, sa[nt]);   // swapped operands -> S^T
      sa[nt] = MFMA16(kb1, qf1, sa[nt]);
    }
    __builtin_amdgcn_s_setprio(0);

    // static-max softmax (exp2); packed b64 Ps writes; mask only on diag
    if (jj != qt) {
#pragma unroll
      for (int nt = 0; nt < 4; ++nt) {
        bf16x4 pk;
#pragma unroll
        for (int g = 0; g < 4; ++g) {
          const float p = exp2f(sa[nt][g] - kMax2);
          lsum += p;
          pk[g] = (bf16)p;
        }
        *(bf16x4*)(&Ps[w][r * PSTR + nt * 16 + quad * 4]) = pk;
      }
    } else {
      const int qloc = w * 16 + r;
#pragma unroll
      for (int nt = 0; nt < 4; ++nt) {
        bf16x4 pk;
#pragma unroll
        for (int g = 0; g < 4; ++g) {
          const float p = (nt * 16 + quad * 4 + g <= qloc)
                              ? exp2f(sa[nt][g] - kMax2) : 0.f;
          lsum += p;
          pk[g] = (bf16)p;
        }
        *(bf16x4*)(&Ps[w][r * PSTR + nt * 16 + quad * 4]) = pk;
      }
    }

    const bf16x8 pa0 = *(const bf16x8*)(&Ps[w][r * PSTR + quad * 8]);
    const bf16x8 pa1 = *(const bf16x8*)(&Ps[w][r * PSTR + 32 + quad * 8]);
    __builtin_amdgcn_s_setprio(1);
#pragma unroll
    for (int dt = 0; dt < 4; ++dt) {
      const int d = dt * 16 + r;
      const bf16x8 vb0 = *(const bf16x8*)(&Vb[d * 64 + ((quad * 8) ^ xk)]);
      const bf16x8 vb1 = *(const bf16x8*)(&Vb[d * 64 + ((quad * 8 + 32) ^ xk)]);
      accO[dt] = MFMA16(pa0, vb0, accO[dt]);
      accO[dt] = MFMA16(pa1, vb1, accO[dt]);
    }
    __builtin_amdgcn_s_setprio(0);
  };

  for (int j = 0; j <= qt; j += 2) {
    __syncthreads();                 // prior pair's fragment reads done (WAR)
    stage(j, 0);
    if (j + 1 <= qt) stage(j + 1, 1);
    __syncthreads();                 // drain async loads (one event per PAIR)
    comp(j, 0);
    if (j + 1 <= qt) comp(j + 1, 1);
  }

  // epilogue: l lives per q=r on lanes {r,r+16,r+32,r+48}; reduce, then
  // redistribute to the accO layout (row q16 = quad*4+reg).
  float l = lsum;
  l += __shfl_xor(l, 16);
  l += __shfl_xor(l, 32);
#pragma unroll
  for (int reg = 0; reg < 4; ++reg) {
    const float inv = 1.0f / __shfl(l, quad * 4 + reg);
    const size_t row = (size_t)(b * Sc + qt * 64 + w * 16 + quad * 4 + reg);
#pragma unroll
    for (int dt = 0; dt < 4; ++dt)
      o[row * (NHc * HDc) + h * HDc + dt * 16 + r] = (bf16)(accO[dt][reg] * inv);
  }
}

// ---------------------------------------------------------------------------
extern "C" void kernel_launch(void* const* d_in, const int* in_sizes, int n_in,
                              void* d_out, int out_size, void* d_ws, size_t ws_size,
                              hipStream_t stream)
{
  const float* hs = (const float*)d_in[0];
  const float* cp = (const float*)d_in[1];
  const float* sp = (const float*)d_in[2];
  const float* Wq = (const float*)d_in[3];
  const float* Wk = (const float*)d_in[4];
  const float* Wv = (const float*)d_in[5];
  const float* Wo = (const float*)d_in[6];
  const float* qw = (const float*)d_in[7];
  const float* kw = (const float*)d_in[8];
  float* out = (float*)d_out;

  char* ws = (char*)d_ws;
  bf16* q_ws  = (bf16*)ws;                      // 16 MiB
  bf16* k_ws  = (bf16*)(ws + (16u << 20));      // 4 MiB
  bf16* vt_ws = (bf16*)(ws + (24u << 20));      // 4 MiB
  bf16* hs_b  = (bf16*)(ws + (28u << 20));      // 16 MiB
  bf16* Wq_b  = (bf16*)(ws + (44u << 20));      // 8 MiB
  bf16* Wk_b  = (bf16*)(ws + (52u << 20));      // 2 MiB
  bf16* Wv_b  = (bf16*)(ws + (54u << 20));      // 2 MiB
  bf16* Wo_b  = (bf16*)(ws + (56u << 20));      // 8 MiB -> 64 MiB total
  bf16* a_ws  = q_ws;                           // safe alias (see attn_fwd)

  dim3 blk(256);
  cvt5<<<dim3(256, 5), blk, 0, stream>>>(
      hs, hs_b, 4096 * 2048, Wq, Wq_b, 2048 * 2048, Wk, Wk_b, 512 * 2048,
      Wv, Wv_b, 512 * 2048, Wo, Wo_b, 2048 * 2048);
  qkv_gemm8<<<dim3(768), blk, 0, stream>>>(hs_b, Wq_b, Wk_b, Wv_b,
                                           q_ws, k_ws, vt_ws, kw, cp, sp);
  attn_fwd<<<dim3(2048), blk, 0, stream>>>(q_ws, k_ws, vt_ws, a_ws, qw, cp, sp);
  o_gemm8<<<dim3(512), blk, 0, stream>>>(a_ws, Wo_b, out);
}

// Round 15
// 294.722 us; speedup vs baseline: 1.0146x; 1.0012x over previous
//
#include <hip/hip_runtime.h>
#include <hip/hip_bf16.h>
#include <stdint.h>

typedef __bf16 bf16;
typedef __bf16 bf16x4 __attribute__((ext_vector_type(4)));
typedef __bf16 bf16x8 __attribute__((ext_vector_type(8)));
typedef float floatx4 __attribute__((ext_vector_type(4)));
typedef float floatx8 __attribute__((ext_vector_type(8)));

#define MFMA16(A, B, C) __builtin_amdgcn_mfma_f32_16x16x32_bf16(A, B, C, 0, 0, 0)

constexpr int Sc = 2048, HIDc = 2048, NHc = 32, NKVc = 8, HDc = 64;
constexpr float kScale = 0.125f;          // HD^-0.5
constexpr float kLog2e = 1.44269504089f;
constexpr float kScale2 = kScale * kLog2e; // folded: S' = S*log2e via Q pre-scale
constexpr float kMax2 = 9.0f * kLog2e;     // static max in log2 units

// async 16B global -> LDS (wave-uniform base + lane*16 on the LDS side)
__device__ __forceinline__ void async16(const bf16* g, bf16* l) {
  __builtin_amdgcn_global_load_lds(
      (const __attribute__((address_space(1))) void*)g,
      (__attribute__((address_space(3))) void*)l, 16, 0, 0);
}

// ---------------------------------------------------------------------------
// f32 -> bf16 conversion for hs + 4 weight matrices (blockIdx.y selects).
// ---------------------------------------------------------------------------
__global__ __launch_bounds__(256)
void cvt5(const float* __restrict__ s0, bf16* __restrict__ d0, int n0,
          const float* __restrict__ s1, bf16* __restrict__ d1, int n1,
          const float* __restrict__ s2, bf16* __restrict__ d2, int n2,
          const float* __restrict__ s3, bf16* __restrict__ d3, int n3,
          const float* __restrict__ s4, bf16* __restrict__ d4, int n4)
{
  const float* s; bf16* d; int n;
  switch (blockIdx.y) {
    case 0: s = s0; d = d0; n = n0; break;
    case 1: s = s1; d = d1; n = n1; break;
    case 2: s = s2; d = d2; n = n2; break;
    case 3: s = s3; d = d3; n = n3; break;
    default: s = s4; d = d4; n = n4; break;
  }
  const size_t stride = (size_t)gridDim.x * blockDim.x * 8;
  for (size_t i = ((size_t)blockIdx.x * blockDim.x + threadIdx.x) * 8;
       i < (size_t)n; i += stride) {
    floatx8 f = *(const floatx8*)(s + i);
    bf16x8 o;
#pragma unroll
    for (int j = 0; j < 8; ++j) o[j] = (bf16)f[j];
    *(bf16x8*)(d + i) = o;
  }
}

// ---------------------------------------------------------------------------
// 128x128 pipelined GEMM core, 256 threads / 4 waves (2x2, 64x64 per wave).
// (unchanged from round 10/13 -- verified, tail-race-fixed)
// ---------------------------------------------------------------------------
__device__ __forceinline__
void gemm128_core(const bf16* __restrict__ A, const bf16* __restrict__ Bw,
                  int K, int m0, int n0, bf16* __restrict__ lds,
                  floatx4 (&acc)[4][4])
{
  constexpr int IH = 128 * 32;      // elements per K-half image (8 KB)

  const int tid  = threadIdx.x;     // 0..255
  const int lane = tid & 63;
  const int w    = tid >> 6;        // 0..3
  const int r    = lane & 15;
  const int quad = lane >> 4;
  const int wm   = w >> 1;          // 2 wave rows
  const int wn   = w & 1;           // 2 wave cols
  const int NT   = K >> 6;

  // staging sources, pre-swizzled: chunk ch=(i*256+tid) -> lrow=ch>>3 (0..63),
  // global slot sl=(ch&7)^(lrow&7); sl>>2 = M-half, sl&3 = 16B K-granule.
  const bf16* gA[2]; const bf16* gB[2];
#pragma unroll
  for (int i = 0; i < 2; ++i) {
    const int ch = i * 256 + tid;
    const int lrow = ch >> 3, sl = (ch & 7) ^ (lrow & 7);
    gA[i] = A  + (size_t)(m0 + (sl >> 2) * 64 + lrow) * K + (sl & 3) * 8;
    gB[i] = Bw + (size_t)(n0 + (sl >> 2) * 64 + lrow) * K + (sl & 3) * 8;
  }

  auto stA = [&](int kt, int s, int kk) {
    bf16* dst = lds + (s * 2 + kk) * IH + tid * 8;
#pragma unroll
    for (int i = 0; i < 2; ++i)
      async16(gA[i] + kt * 64 + kk * 32, dst + i * 2048);
  };
  auto stB = [&](int kt, int s, int kk) {
    bf16* dst = lds + 4 * IH + (s * 2 + kk) * IH + tid * 8;
#pragma unroll
    for (int i = 0; i < 2; ++i)
      async16(gB[i] + kt * 64 + kk * 32, dst + i * 2048);
  };

  // read offsets: frag (mt): lrow = mt*16 + r, slot = ((half<<2)+quad)^(r&7)
  const int aoff = r * 64 + (((wm << 2) + quad) ^ (r & 7)) * 8;
  const int boff = r * 64 + (((wn << 2) + quad) ^ (r & 7)) * 8;

  bf16x8 a[4], b[4];

#define LDA(S, KK) do { const bf16* _p = lds + ((S) * 2 + (KK)) * IH + aoff; \
  _Pragma("unroll") for (int m2 = 0; m2 < 4; ++m2) a[m2] = *(const bf16x8*)(_p + m2 * 1024); } while (0)
#define LDB(S, KK) do { const bf16* _p = lds + 4 * IH + ((S) * 2 + (KK)) * IH + boff; \
  _Pragma("unroll") for (int n2 = 0; n2 < 4; ++n2) b[n2] = *(const bf16x8*)(_p + n2 * 1024); } while (0)
#define MM() do { __builtin_amdgcn_s_setprio(1); \
  _Pragma("unroll") for (int m2 = 0; m2 < 4; ++m2) \
    _Pragma("unroll") for (int n2 = 0; n2 < 4; ++n2) \
      acc[m2][n2] = MFMA16(a[m2], b[n2], acc[m2][n2]); \
  __builtin_amdgcn_s_setprio(0); } while (0)
#define BAR() asm volatile("s_barrier" ::: "memory")

  // prologue: tile0 complete + tile1's kk0; certify tile0 (vmcnt(4) leaves
  // exactly the 4 t1-kk0 loads in flight)
  stA(0, 0, 0); stB(0, 0, 0); stA(0, 0, 1); stB(0, 0, 1);
  stA(1, 1, 0); stB(1, 1, 0);
  asm volatile("s_waitcnt vmcnt(4)" ::: "memory"); BAR();

  for (int t = 0; t < NT; ++t) {
    const int s = t & 1;
    // Phase A (kk0) + stage next tile's kk1
    LDA(s, 0); LDB(s, 0);
    if (t + 1 < NT) { stA(t + 1, s ^ 1, 1); stB(t + 1, s ^ 1, 1); }
    BAR(); MM(); BAR();
    // Phase B (kk1) + stage tile t+2's kk0
    LDA(s, 1); LDB(s, 1);
    if (t + 2 < NT) { stA(t + 2, s, 0); stB(t + 2, s, 0); }
    BAR(); MM();
    // gate: certify tile t+1's four halves. Counted only while S_B(t) was
    // issued; otherwise FULL drain (tail-race fix, verified r10).
    if (t + 2 < NT) asm volatile("s_waitcnt vmcnt(4)" ::: "memory");
    else            asm volatile("s_waitcnt vmcnt(0)" ::: "memory");
    BAR();
  }

#undef LDA
#undef LDB
#undef MM
#undef BAR
}

// ---- epilogues (wave tile 64x64: row base wm*64, col base wn*64) -----------
template<bool CF32>
__device__ __forceinline__
void epi_plain(const floatx4 (&acc)[4][4], void* C, int N, int m0, int n0,
               int wm, int wn, int r, int quad)
{
#pragma unroll
  for (int mt = 0; mt < 4; ++mt) {
#pragma unroll
    for (int nt = 0; nt < 4; ++nt) {
      const int row = m0 + wm * 64 + mt * 16 + quad * 4;
      const int col = n0 + wn * 64 + nt * 16 + r;
#pragma unroll
      for (int g = 0; g < 4; ++g) {
        const size_t ci = (size_t)(row + g) * N + col;
        if constexpr (CF32) ((float*)C)[ci] = acc[mt][nt][g];
        else                ((bf16*)C)[ci]  = (bf16)acc[mt][nt][g];
      }
    }
  }
}

// K path: fused RMSNorm (f32 acc) + RoPE, store bf16 to k_ws [token][h*64+d].
__device__ __forceinline__
void epi_k(const floatx4 (&acc)[4][4], bf16* kws, const float* kw,
           const float* cp, const float* sp, int m0, int n0,
           int wm, int wn, int r, int quad)
{
  const int h = (n0 >> 6) + wn;                    // 0..7
  const float w0 = kw[r], w1 = kw[16 + r], w2 = kw[32 + r], w3 = kw[48 + r];
#pragma unroll
  for (int mt = 0; mt < 4; ++mt) {
#pragma unroll
    for (int g = 0; g < 4; ++g) {
      const int row = m0 + wm * 64 + mt * 16 + quad * 4 + g;
      const float x0 = acc[mt][0][g], x1 = acc[mt][1][g];
      const float x2 = acc[mt][2][g], x3 = acc[mt][3][g];
      float ss = x0 * x0 + x1 * x1 + x2 * x2 + x3 * x3;
      ss += __shfl_xor(ss, 1); ss += __shfl_xor(ss, 2);
      ss += __shfl_xor(ss, 4); ss += __shfl_xor(ss, 8);
      const float rr = rsqrtf(ss * (1.0f / 64.0f) + 1e-6f);
      const float y0 = x0 * rr * w0, y1 = x1 * rr * w1;
      const float y2 = x2 * rr * w2, y3 = x3 * rr * w3;
      const float* cb = cp + (size_t)row * 64 + r;
      const float* sb = sp + (size_t)row * 64 + r;
      bf16* p = kws + (size_t)row * 512 + h * 64 + r;
      p[0]  = (bf16)(y0 * cb[0]  - y2 * sb[0]);
      p[16] = (bf16)(y1 * cb[16] - y3 * sb[16]);
      p[32] = (bf16)(y2 * cb[32] + y0 * sb[32]);
      p[48] = (bf16)(y3 * cb[48] + y1 * sb[48]);
    }
  }
}

// V path: store transposed directly into vt [((b*8+kvh)*64+d)*2048 + s].
__device__ __forceinline__
void epi_v(const floatx4 (&acc)[4][4], bf16* vt, int m0, int n0,
           int wm, int wn, int r, int quad)
{
  const int kvh = (n0 >> 6) + wn;                  // 0..7
  const int b   = m0 >> 11;
  const int sb  = (m0 & 2047) + wm * 64 + quad * 4;
#pragma unroll
  for (int mt = 0; mt < 4; ++mt) {
#pragma unroll
    for (int nt = 0; nt < 4; ++nt) {
      const int d = nt * 16 + r;
      bf16x4 pk;
#pragma unroll
      for (int g = 0; g < 4; ++g) pk[g] = (bf16)acc[mt][nt][g];
      *(bf16x4*)(vt + ((size_t)((b * 8 + kvh) * 64 + d)) * Sc + sb + mt * 16) = pk;
    }
  }
}

__global__ __launch_bounds__(256, 2)
void qkv_gemm8(const bf16* __restrict__ hs,
               const bf16* __restrict__ Wq, const bf16* __restrict__ Wk,
               const bf16* __restrict__ Wv,
               bf16* __restrict__ q_ws, bf16* __restrict__ k_ws,
               bf16* __restrict__ vt_ws,
               const float* __restrict__ kw, const float* __restrict__ cp,
               const float* __restrict__ sp)
{
  __shared__ bf16 lds[8 * 128 * 32];               // 64 KiB -> 2 blocks/CU
  const int wg  = blockIdx.x;
  const int swz = (wg & 7) * 96 + (wg >> 3);       // 768 blocks, bijective
  const int mi  = swz / 24, ni = swz % 24;
  const bf16* Bw; int n0;
  if (ni < 16)      { Bw = Wq; n0 = ni * 128; }
  else if (ni < 20) { Bw = Wk; n0 = (ni - 16) * 128; }
  else              { Bw = Wv; n0 = (ni - 20) * 128; }

  floatx4 acc[4][4] = {};
  gemm128_core(hs, Bw, HIDc, mi * 128, n0, lds, acc);

  const int lane = threadIdx.x & 63, w = threadIdx.x >> 6;
  const int r = lane & 15, quad = lane >> 4;
  const int wm = w >> 1, wn = w & 1;
  if (ni < 16)
    epi_plain<false>(acc, q_ws, 2048, mi * 128, n0, wm, wn, r, quad);
  else if (ni < 20)
    epi_k(acc, k_ws, kw, cp, sp, mi * 128, n0, wm, wn, r, quad);
  else
    epi_v(acc, vt_ws, mi * 128, n0, wm, wn, r, quad);
}

__global__ __launch_bounds__(256, 2)
void o_gemm8(const bf16* __restrict__ a_ws, const bf16* __restrict__ Wo,
             float* __restrict__ out)
{
  __shared__ bf16 lds[8 * 128 * 32];               // 64 KiB -> 2 blocks/CU
  const int wg  = blockIdx.x;
  const int swz = (wg & 7) * 64 + (wg >> 3);       // 512 blocks, bijective
  const int mi  = swz >> 4, ni = swz & 15;

  floatx4 acc[4][4] = {};
  gemm128_core(a_ws, Wo, NHc * HDc, mi * 128, ni * 128, lds, acc);

  const int lane = threadIdx.x & 63, w = threadIdx.x >> 6;
  const int r = lane & 15, quad = lane >> 4;
  const int wm = w >> 1, wn = w & 1;
  epi_plain<true>(acc, out, HIDc, mi * 128, ni * 128, wm, wn, r, quad);
}

// ---------------------------------------------------------------------------
// Causal flash attention, GQA groups=4, fused Q RMSNorm+RoPE, static-max
// softmax in LOG2 units, swapped QK^T (S^T; packed b64 Ps writes).
// r15 = exact r13 structure (verified 77.4us: single-buffer staging, 2048
// blocks, LDS 25600, stride-72 Ps -- r14 falsified both pair-staging and the
// Ps-stride conflict theory: conflicts identical at 72/88 and benign) with
// ONE change: l-via-MFMA. r13/r14 counters show VALUBusy 58% dominant; the
// 16 serial lsum += p per tile-step are a 16-deep dependent fp32 chain
// (~64cy latency, non-reassociable). Replaced by 2 extra MFMA per step
// (A=pa, B=ones): lacc[g] accumulates exact row-sums of P (masked zeros
// contribute 0) in the SAME reg->q layout as accO, so the epilogue is just
// inv = 1/lacc[reg] -- no lane shuffles. MFMA pipe is 18% utilized; free.
// o aliases q (block-exclusive regions).
// ---------------------------------------------------------------------------
__global__ __launch_bounds__(256, 6)
void attn_fwd(const bf16* __restrict__ q, const bf16* __restrict__ k,
              const bf16* __restrict__ vt, bf16* __restrict__ o,
              const float* __restrict__ qw, const float* __restrict__ cp,
              const float* __restrict__ sp)
{
  __shared__ bf16 Ks[64 * 64];
  __shared__ bf16 Vs[64 * 64];        // V^T [d][kv], swizzled
  __shared__ bf16 Ps[4][16 * 72];     // per-wave P round-trip, stride 72

  const int bi  = blockIdx.x;          // 0..2047
  const int qt  = 31 - (bi >> 6);      // heavy q-tiles first in dispatch order
  const int hb  = bi & 63;
  const int h   = hb & 31;
  const int b   = hb >> 5;
  const int kvh = h >> 2;
  const int tid = threadIdx.x, lane = tid & 63, w = tid >> 6;
  const int r = lane & 15, quad = lane >> 4;

  // Q load + fused RMSNorm (kScale2 = scale*log2e folded in) + RoPE
  const floatx8 w0 = *(const floatx8*)(qw + quad * 8);
  const floatx8 w1 = *(const floatx8*)(qw + 32 + quad * 8);
  bf16x8 qf0, qf1;
  {
    const int m = b * Sc + qt * 64 + w * 16 + r;
    const bf16* qp = q + (size_t)m * (NHc * HDc) + h * HDc + quad * 8;
    bf16x8 x0 = *(const bf16x8*)qp;
    bf16x8 x1 = *(const bf16x8*)(qp + 32);
    float ss = 0.f;
#pragma unroll
    for (int i = 0; i < 8; ++i)
      ss += (float)x0[i] * (float)x0[i] + (float)x1[i] * (float)x1[i];
    ss += __shfl_xor(ss, 16);
    ss += __shfl_xor(ss, 32);
    const float rq = rsqrtf(ss * (1.0f / 64.0f) + 1e-6f) * kScale2;
    const floatx8 c0 = *(const floatx8*)(cp + (size_t)m * 64 + quad * 8);
    const floatx8 c1 = *(const floatx8*)(cp + (size_t)m * 64 + 32 + quad * 8);
    const floatx8 s0 = *(const floatx8*)(sp + (size_t)m * 64 + quad * 8);
    const floatx8 s1 = *(const floatx8*)(sp + (size_t)m * 64 + 32 + quad * 8);
#pragma unroll
    for (int i = 0; i < 8; ++i) {
      const float y0 = (float)x0[i] * rq * w0[i];
      const float y1 = (float)x1[i] * rq * w1[i];
      qf0[i] = (bf16)(y0 * c0[i] - y1 * s0[i]);   // d < 32
      qf1[i] = (bf16)(y1 * c1[i] + y0 * s1[i]);   // d >= 32
    }
  }

  bf16x8 kOnes;
#pragma unroll
  for (int i = 0; i < 8; ++i) kOnes[i] = (bf16)1.0f;

  floatx4 accO[4] = {};
  floatx4 lacc = {};                   // l via MFMA: lacc[g] = l for q16=quad*4+g

  const int kvr = tid >> 3;            // staging row (0..31), +32 for seg1
  const int cx  = ((tid & 7) * 8) ^ (8 * (kvr & 7));  // swizzle on GLOBAL side
  const int xk  = 8 * (r & 7);                        // read-side XOR

  const bf16* kp = k + (size_t)b * Sc * (NKVc * HDc) + kvh * HDc;
  const bf16* vp = vt + ((size_t)((b * NKVc + kvh) * 64)) * Sc;

  for (int j = 0; j <= qt; ++j) {
    __syncthreads();                 // prior tile's fragment reads done (WAR)
    {
      const bf16* kj = kp + (size_t)j * 64 * (NKVc * HDc);
      const bf16* vj = vp + j * 64;
      async16(kj + (size_t)kvr * (NKVc * HDc) + cx, Ks + tid * 8);
      async16(kj + (size_t)(kvr + 32) * (NKVc * HDc) + cx, Ks + (tid + 256) * 8);
      async16(vj + (size_t)kvr * Sc + cx, Vs + tid * 8);
      async16(vj + (size_t)(kvr + 32) * Sc + cx, Vs + (tid + 256) * 8);
    }
    __syncthreads();                 // drain async loads

    // S^T = K Q^T (64 x 16 per wave), pre-scaled in log2 units.
    // Thread (r,quad) reg g of sa[nt] = S[q=r][kv=16nt+4quad+g].
    floatx4 sa[4];
#pragma unroll
    for (int nt = 0; nt < 4; ++nt) sa[nt] = floatx4{0.f, 0.f, 0.f, 0.f};
    __builtin_amdgcn_s_setprio(1);
#pragma unroll
    for (int nt = 0; nt < 4; ++nt) {
      const int kv = nt * 16 + r;
      const bf16x8 kb0 = *(const bf16x8*)(&Ks[kv * 64 + ((quad * 8) ^ xk)]);
      const bf16x8 kb1 = *(const bf16x8*)(&Ks[kv * 64 + ((quad * 8 + 32) ^ xk)]);
      sa[nt] = MFMA16(kb0, qf0, sa[nt]);   // swapped operands -> S^T
      sa[nt] = MFMA16(kb1, qf1, sa[nt]);
    }
    __builtin_amdgcn_s_setprio(0);

    // static-max softmax (exp2); packed b64 Ps writes; mask only on diag.
    // No scalar lsum chain -- l accumulated via MFMA below.
    if (j != qt) {
#pragma unroll
      for (int nt = 0; nt < 4; ++nt) {
        bf16x4 pk;
#pragma unroll
        for (int g = 0; g < 4; ++g) pk[g] = (bf16)exp2f(sa[nt][g] - kMax2);
        *(bf16x4*)(&Ps[w][r * 72 + nt * 16 + quad * 4]) = pk;
      }
    } else {
      const int qloc = w * 16 + r;
#pragma unroll
      for (int nt = 0; nt < 4; ++nt) {
        bf16x4 pk;
#pragma unroll
        for (int g = 0; g < 4; ++g)
          pk[g] = (bf16)((nt * 16 + quad * 4 + g <= qloc)
                             ? exp2f(sa[nt][g] - kMax2) : 0.f);
        *(bf16x4*)(&Ps[w][r * 72 + nt * 16 + quad * 4]) = pk;
      }
    }

    const bf16x8 pa0 = *(const bf16x8*)(&Ps[w][r * 72 + quad * 8]);
    const bf16x8 pa1 = *(const bf16x8*)(&Ps[w][r * 72 + 32 + quad * 8]);
    __builtin_amdgcn_s_setprio(1);
#pragma unroll
    for (int dt = 0; dt < 4; ++dt) {
      const int d = dt * 16 + r;
      const bf16x8 vb0 = *(const bf16x8*)(&Vs[d * 64 + ((quad * 8) ^ xk)]);
      const bf16x8 vb1 = *(const bf16x8*)(&Vs[d * 64 + ((quad * 8 + 32) ^ xk)]);
      accO[dt] = MFMA16(pa0, vb0, accO[dt]);
      accO[dt] = MFMA16(pa1, vb1, accO[dt]);
    }
    lacc = MFMA16(pa0, kOnes, lacc);   // row-sums of P, same reg->q layout
    lacc = MFMA16(pa1, kOnes, lacc);
    __builtin_amdgcn_s_setprio(0);
  }

  // epilogue: lacc[reg] = l for row q16 = quad*4+reg (uniform across r)
#pragma unroll
  for (int reg = 0; reg < 4; ++reg) {
    const float inv = 1.0f / lacc[reg];
    const size_t row = (size_t)(b * Sc + qt * 64 + w * 16 + quad * 4 + reg);
#pragma unroll
    for (int dt = 0; dt < 4; ++dt)
      o[row * (NHc * HDc) + h * HDc + dt * 16 + r] = (bf16)(accO[dt][reg] * inv);
  }
}

// ---------------------------------------------------------------------------
extern "C" void kernel_launch(void* const* d_in, const int* in_sizes, int n_in,
                              void* d_out, int out_size, void* d_ws, size_t ws_size,
                              hipStream_t stream)
{
  const float* hs = (const float*)d_in[0];
  const float* cp = (const float*)d_in[1];
  const float* sp = (const float*)d_in[2];
  const float* Wq = (const float*)d_in[3];
  const float* Wk = (const float*)d_in[4];
  const float* Wv = (const float*)d_in[5];
  const float* Wo = (const float*)d_in[6];
  const float* qw = (const float*)d_in[7];
  const float* kw = (const float*)d_in[8];
  float* out = (float*)d_out;

  char* ws = (char*)d_ws;
  bf16* q_ws  = (bf16*)ws;                      // 16 MiB
  bf16* k_ws  = (bf16*)(ws + (16u << 20));      // 4 MiB
  bf16* vt_ws = (bf16*)(ws + (24u << 20));      // 4 MiB
  bf16* hs_b  = (bf16*)(ws + (28u << 20));      // 16 MiB
  bf16* Wq_b  = (bf16*)(ws + (44u << 20));      // 8 MiB
  bf16* Wk_b  = (bf16*)(ws + (52u << 20));      // 2 MiB
  bf16* Wv_b  = (bf16*)(ws + (54u << 20));      // 2 MiB
  bf16* Wo_b  = (bf16*)(ws + (56u << 20));      // 8 MiB -> 64 MiB total
  bf16* a_ws  = q_ws;                           // safe alias (see attn_fwd)

  dim3 blk(256);
  cvt5<<<dim3(256, 5), blk, 0, stream>>>(
      hs, hs_b, 4096 * 2048, Wq, Wq_b, 2048 * 2048, Wk, Wk_b, 512 * 2048,
      Wv, Wv_b, 512 * 2048, Wo, Wo_b, 2048 * 2048);
  qkv_gemm8<<<dim3(768), blk, 0, stream>>>(hs_b, Wq_b, Wk_b, Wv_b,
                                           q_ws, k_ws, vt_ws, kw, cp, sp);
  attn_fwd<<<dim3(2048), blk, 0, stream>>>(q_ws, k_ws, vt_ws, a_ws, qw, cp, sp);
  o_gemm8<<<dim3(512), blk, 0, stream>>>(a_ws, Wo_b, out);
}